// Round 1
// baseline (939.715 us; speedup 1.0000x reference)
//
#include <hip/hip_runtime.h>
#include <math.h>

#define N_NODES 100000
#define N_EDGES 1600000
// D_IN = D_HID = 128, D_OUT = 64

// ---------------------------------------------------------------------------
// Edge-index dtype detection: reference says int64, harness doc says int32.
// If the buffer is int64, every odd 32-bit word (high word) is 0 (values <1e5).
// If int32, odd words are real random indices (~all nonzero). flag=1 -> int64.
__global__ void k_detect(const int* __restrict__ ei, int* __restrict__ flag, int host_hint) {
    __shared__ int s_cnt;
    if (threadIdx.x == 0) s_cnt = 0;
    __syncthreads();
    int local = 0;
    for (int e = threadIdx.x; e < 4096; e += blockDim.x)
        if (ei[2 * e + 1] != 0) local++;
    atomicAdd(&s_cnt, local);
    __syncthreads();
    if (threadIdx.x == 0) flag[0] = (host_hint || s_cnt < 100) ? 1 : 0;
}

__global__ void k_normalize(const int* __restrict__ ei32, const int* __restrict__ flag,
                            int* __restrict__ rows, int* __restrict__ cols) {
    int e = blockIdx.x * blockDim.x + threadIdx.x;
    if (e >= N_EDGES) return;
    if (flag[0]) {
        const long long* ei64 = (const long long*)ei32;
        rows[e] = (int)ei64[e];
        cols[e] = (int)ei64[N_EDGES + e];
    } else {
        rows[e] = ei32[e];
        cols[e] = ei32[N_EDGES + e];
    }
}

// ---------------------------------------------------------------------------
// deg starts at 1.0 (self loop weight); cnt = per-destination edge count.
__global__ void k_init(float* __restrict__ deg, int* __restrict__ cnt) {
    int i = blockIdx.x * blockDim.x + threadIdx.x;
    if (i < N_NODES) { deg[i] = 1.0f; cnt[i] = 0; }
}

__global__ void k_deg_hist(const int* __restrict__ cols, const float* __restrict__ w,
                           float* __restrict__ deg, int* __restrict__ cnt) {
    int e = blockIdx.x * blockDim.x + threadIdx.x;
    if (e >= N_EDGES) return;
    int c = cols[e];
    atomicAdd(&deg[c], w[e]);
    atomicAdd(&cnt[c], 1);
}

__global__ void k_dinv(float* __restrict__ deg) {
    int i = blockIdx.x * blockDim.x + threadIdx.x;
    if (i < N_NODES) deg[i] = 1.0f / sqrtf(deg[i]);   // deg >= 1 always
}

// ---------------------------------------------------------------------------
// Exclusive prefix sum of cnt -> off (and a scatter cursor copy).
// Single block of 1024: per-wave shfl scan + 16-entry wave-sum scan.
__global__ __launch_bounds__(1024) void k_scan(const int* __restrict__ cnt,
                                               int* __restrict__ off,
                                               int* __restrict__ cursor) {
    __shared__ int swave[16];
    __shared__ int swex[16];
    __shared__ int s_carry;
    const int tid = threadIdx.x;
    const int lane = tid & 63;
    const int w = tid >> 6;
    if (tid == 0) s_carry = 0;
    __syncthreads();
    for (int base = 0; base < N_NODES; base += 1024) {
        int i = base + tid;
        int v = (i < N_NODES) ? cnt[i] : 0;
        int x = v;
        #pragma unroll
        for (int s = 1; s < 64; s <<= 1) {
            int t = __shfl_up(x, s);
            if (lane >= s) x += t;
        }
        if (lane == 63) swave[w] = x;
        __syncthreads();
        if (w == 0) {   // all 64 lanes of wave 0 run the shfl (defined behavior)
            int orig = (lane < 16) ? swave[lane] : 0;
            int y = orig;
            #pragma unroll
            for (int s = 1; s < 16; s <<= 1) {
                int t = __shfl_up(y, s);
                if (lane >= s) y += t;
            }
            if (lane < 16) swex[lane] = y - orig;   // exclusive wave offsets
        }
        __syncthreads();
        int carry = s_carry;
        int excl = carry + swex[w] + (x - v);
        if (i < N_NODES) { off[i] = excl; cursor[i] = excl; }
        __syncthreads();
        if (tid == 1023) s_carry = carry + swex[15] + x;  // += chunk total
        __syncthreads();
    }
}

// ---------------------------------------------------------------------------
// Bucket edges by destination; store (src, normalized coefficient) packed 8B.
__global__ void k_scatter(const int* __restrict__ rows, const int* __restrict__ cols,
                          const float* __restrict__ w, const float* __restrict__ dinv,
                          int* __restrict__ cursor, int2* __restrict__ sedge) {
    int e = blockIdx.x * blockDim.x + threadIdx.x;
    if (e >= N_EDGES) return;
    int r = rows[e], c = cols[e];
    float coef = dinv[r] * w[e] * dinv[c];
    int p = atomicAdd(&cursor[c], 1);
    sedge[p] = make_int2(r, __float_as_int(coef));
}

// ---------------------------------------------------------------------------
// C[n,DOUT] = A[n,128] @ W[128,DOUT]; optional fused bias+sigmoid epilogue.
// Block: 256 threads (16x16), tile 128 rows x DOUT cols, W fully in LDS.
template <int DOUT, bool SIG>
__global__ __launch_bounds__(256) void k_gemm(const float* __restrict__ A,
                                              const float* __restrict__ W,
                                              const float* __restrict__ bias,
                                              float* __restrict__ C) {
    constexpr int CPT = DOUT / 16;        // cols per thread: 8 (D=128) or 4 (D=64)
    __shared__ float Ws[128 * DOUT];      // 64KB / 32KB
    __shared__ float As[8][128];          // k-chunk of A, transposed [kk][row]
    const int tid = threadIdx.x;
    const int tx = tid & 15, ty = tid >> 4;

    for (int i = tid * 4; i < 128 * DOUT; i += 256 * 4)
        *(float4*)&Ws[i] = *(const float4*)&W[i];

    const int r0 = blockIdx.x * 128;
    const int arow = tid >> 1;            // 0..127
    const int ak = (tid & 1) * 4;         // 0 or 4
    const bool rowok = (r0 + arow) < N_NODES;

    float acc[8][CPT];
    #pragma unroll
    for (int i = 0; i < 8; i++)
        #pragma unroll
        for (int j = 0; j < CPT; j++) acc[i][j] = 0.f;

    for (int k0 = 0; k0 < 128; k0 += 8) {
        float4 av = make_float4(0.f, 0.f, 0.f, 0.f);
        if (rowok) av = *(const float4*)&A[(size_t)(r0 + arow) * 128 + k0 + ak];
        __syncthreads();                  // prev As reads done (and Ws ready, iter 0)
        As[ak + 0][arow] = av.x;
        As[ak + 1][arow] = av.y;
        As[ak + 2][arow] = av.z;
        As[ak + 3][arow] = av.w;
        __syncthreads();
        #pragma unroll
        for (int kk = 0; kk < 8; kk++) {
            float4 a0 = *(const float4*)&As[kk][ty * 8];
            float4 a1 = *(const float4*)&As[kk][ty * 8 + 4];
            float av8[8] = {a0.x, a0.y, a0.z, a0.w, a1.x, a1.y, a1.z, a1.w};
            float wv[CPT];
            float4 w0 = *(const float4*)&Ws[(k0 + kk) * DOUT + tx * CPT];
            wv[0] = w0.x; wv[1] = w0.y; wv[2] = w0.z; wv[3] = w0.w;
            if constexpr (CPT == 8) {
                float4 w1 = *(const float4*)&Ws[(k0 + kk) * DOUT + tx * CPT + 4];
                wv[4] = w1.x; wv[5] = w1.y; wv[6] = w1.z; wv[7] = w1.w;
            }
            #pragma unroll
            for (int i = 0; i < 8; i++)
                #pragma unroll
                for (int j = 0; j < CPT; j++)
                    acc[i][j] = fmaf(av8[i], wv[j], acc[i][j]);
        }
    }

    #pragma unroll
    for (int i = 0; i < 8; i++) {
        int r = r0 + ty * 8 + i;
        if (r < N_NODES) {
            float vout[CPT];
            #pragma unroll
            for (int j = 0; j < CPT; j++) {
                float v = acc[i][j];
                if constexpr (SIG) {
                    v += bias[tx * CPT + j];
                    v = 1.0f / (1.0f + expf(-v));
                }
                vout[j] = v;
            }
            #pragma unroll
            for (int j = 0; j < CPT; j += 4)
                *(float4*)&C[(size_t)r * DOUT + tx * CPT + j] =
                    make_float4(vout[j], vout[j + 1], vout[j + 2], vout[j + 3]);
        }
    }
}

// ---------------------------------------------------------------------------
// Pull aggregation: one wave per destination node; lane owns 2 of 128 dims.
// acc = dinv[i]^2 * lin[i] + sum_e coef_e * lin[src_e]; out = relu(acc + b).
__global__ __launch_bounds__(256) void k_aggregate(const float* __restrict__ lin,
                                                   const int2* __restrict__ sedge,
                                                   const int* __restrict__ off,
                                                   const int* __restrict__ cnt,
                                                   const float* __restrict__ dinv,
                                                   const float* __restrict__ bias,
                                                   float* __restrict__ out) {
    const int node = (blockIdx.x * 256 + threadIdx.x) >> 6;
    const int lane = threadIdx.x & 63;
    if (node >= N_NODES) return;
    const float di = dinv[node];
    const size_t base = (size_t)node * 128 + lane * 2;
    float2 sv = *(const float2*)&lin[base];
    float ax = di * di * sv.x;
    float ay = di * di * sv.y;
    const int start = off[node];
    const int end = start + cnt[node];
    for (int e = start; e < end; e++) {
        int2 ed = sedge[e];                       // same addr across wave: broadcast
        float cf = __int_as_float(ed.y);
        float2 v = *(const float2*)&lin[(size_t)ed.x * 128 + lane * 2];  // 512B coalesced
        ax = fmaf(cf, v.x, ax);
        ay = fmaf(cf, v.y, ay);
    }
    float2 bv = *(const float2*)&bias[lane * 2];
    ax = fmaxf(ax + bv.x, 0.f);
    ay = fmaxf(ay + bv.y, 0.f);
    *(float2*)&out[base] = make_float2(ax, ay);
}

// ---------------------------------------------------------------------------
extern "C" void kernel_launch(void* const* d_in, const int* in_sizes, int n_in,
                              void* d_out, int out_size, void* d_ws, size_t ws_size,
                              hipStream_t stream) {
    const float* x   = (const float*)d_in[0];
    const int*   ei  = (const int*)d_in[1];
    const float* ew  = (const float*)d_in[2];
    const float* W1  = (const float*)d_in[3];
    const float* b1  = (const float*)d_in[4];
    const float* W2  = (const float*)d_in[5];
    const float* b2  = (const float*)d_in[6];
    const float* Wfc = (const float*)d_in[7];
    const float* bfc = (const float*)d_in[8];
    float* out = (float*)d_out;

    // Workspace layout (~129 MB), 256B-aligned slices. Re-poisoned each launch;
    // every slice below is fully initialized before being read.
    char* ws = (char*)d_ws;
    size_t o = 0;
    auto alloc = [&](size_t bytes) { char* p = ws + o; o += (bytes + 255) & ~255ull; return p; };
    float* deg   = (float*)alloc((size_t)N_NODES * 4);   // becomes dinv in-place
    int*   cnt   = (int*)  alloc((size_t)N_NODES * 4);
    int*   off   = (int*)  alloc((size_t)N_NODES * 4);
    int*   cur   = (int*)  alloc((size_t)N_NODES * 4);
    int*   flag  = (int*)  alloc(256);
    int*   rows  = (int*)  alloc((size_t)N_EDGES * 4);
    int*   cols  = (int*)  alloc((size_t)N_EDGES * 4);
    int2*  sedge = (int2*) alloc((size_t)N_EDGES * 8);
    float* bufA  = (float*)alloc((size_t)N_NODES * 128 * 4);
    float* bufB  = (float*)alloc((size_t)N_NODES * 128 * 4);

    const int EB = (N_EDGES + 255) / 256;
    const int NB = (N_NODES + 255) / 256;

    // edge_index dtype: if harness counted int64 bytes as int32 elements we see 4*E.
    int hint64 = (in_sizes[1] == 4 * N_EDGES) ? 1 : 0;
    k_detect<<<1, 256, 0, stream>>>(ei, flag, hint64);
    k_normalize<<<EB, 256, 0, stream>>>(ei, flag, rows, cols);

    k_init<<<NB, 256, 0, stream>>>(deg, cnt);
    k_deg_hist<<<EB, 256, 0, stream>>>(cols, ew, deg, cnt);
    k_dinv<<<NB, 256, 0, stream>>>(deg);
    k_scan<<<1, 1024, 0, stream>>>(cnt, off, cur);
    k_scatter<<<EB, 256, 0, stream>>>(rows, cols, ew, deg, cur, sedge);

    const int GB = (N_NODES + 127) / 128;        // 782
    const int AB = (N_NODES * 64 + 255) / 256;   // 25000 (1 wave / node)

    k_gemm<128, false><<<GB, 256, 0, stream>>>(x, W1, nullptr, bufA);
    k_aggregate<<<AB, 256, 0, stream>>>(bufA, sedge, off, cnt, deg, b1, bufB);
    k_gemm<128, false><<<GB, 256, 0, stream>>>(bufB, W2, nullptr, bufA);
    k_aggregate<<<AB, 256, 0, stream>>>(bufA, sedge, off, cnt, deg, b2, bufB);
    k_gemm<64, true><<<GB, 256, 0, stream>>>(bufB, Wfc, bfc, out);
}

// Round 2
// 752.738 us; speedup vs baseline: 1.2484x; 1.2484x over previous
//
#include <hip/hip_runtime.h>
#include <math.h>

#define N_NODES 100000
#define N_EDGES 1600000
#define SCAN_CHUNK 1024
#define NSCAN ((N_NODES + SCAN_CHUNK - 1) / SCAN_CHUNK)   // 98
// D_IN = D_HID = 128, D_OUT = 64

// ---------------------------------------------------------------------------
// Edge-index dtype detection (int64 per reference vs int32 per harness doc).
// int64 buffer -> odd 32-bit words (high words) are all 0 (indices < 1e5).
__global__ void k_detect(const int* __restrict__ ei, int* __restrict__ flag, int host_hint) {
    __shared__ int s_cnt;
    if (threadIdx.x == 0) s_cnt = 0;
    __syncthreads();
    int local = 0;
    for (int e = threadIdx.x; e < 4096; e += blockDim.x)
        if (ei[2 * e + 1] != 0) local++;
    atomicAdd(&s_cnt, local);
    __syncthreads();
    if (threadIdx.x == 0) flag[0] = (host_hint || s_cnt < 100) ? 1 : 0;
}

__global__ void k_init(float* __restrict__ deg, int* __restrict__ cnt) {
    int i = blockIdx.x * blockDim.x + threadIdx.x;
    if (i < N_NODES) { deg[i] = 1.0f; cnt[i] = 0; }   // 1.0 = self-loop weight
}

// Fused: decode edge_index + degree/count histogram in one pass.
__global__ void k_norm_hist(const int* __restrict__ ei32, const int* __restrict__ flag,
                            const float* __restrict__ w,
                            int* __restrict__ rows, int* __restrict__ cols,
                            float* __restrict__ deg, int* __restrict__ cnt) {
    int e = blockIdx.x * blockDim.x + threadIdx.x;
    if (e >= N_EDGES) return;
    int r, c;
    if (flag[0]) {
        const long long* ei64 = (const long long*)ei32;
        r = (int)ei64[e];
        c = (int)ei64[N_EDGES + e];
    } else {
        r = ei32[e];
        c = ei32[N_EDGES + e];
    }
    rows[e] = r;
    cols[e] = c;
    atomicAdd(&deg[c], w[e]);
    atomicAdd(&cnt[c], 1);
}

__global__ void k_dinv(float* __restrict__ deg) {
    int i = blockIdx.x * blockDim.x + threadIdx.x;
    if (i < N_NODES) deg[i] = 1.0f / sqrtf(deg[i]);   // deg >= 1 always
}

// ---------------------------------------------------------------------------
// Multi-block exclusive scan of cnt -> off (+ cursor copy). 3 small kernels.
__global__ __launch_bounds__(256) void k_scan_a(const int* __restrict__ cnt,
                                                int* __restrict__ bsum) {
    __shared__ int sred[4];
    const int b = blockIdx.x, tid = threadIdx.x;
    const int base = b * SCAN_CHUNK;
    int s = 0;
    #pragma unroll
    for (int i = 0; i < 4; i++) {
        int idx = base + tid + i * 256;
        if (idx < N_NODES) s += cnt[idx];
    }
    #pragma unroll
    for (int sh = 1; sh < 64; sh <<= 1) s += __shfl_xor(s, sh);
    if ((tid & 63) == 0) sred[tid >> 6] = s;
    __syncthreads();
    if (tid == 0) bsum[b] = sred[0] + sred[1] + sred[2] + sred[3];
}

__global__ __launch_bounds__(128) void k_scan_b(const int* __restrict__ bsum,
                                                int* __restrict__ bex) {
    __shared__ int wsum[2];
    const int tid = threadIdx.x, lane = tid & 63, w = tid >> 6;
    int v = (tid < NSCAN) ? bsum[tid] : 0;
    int x = v;
    #pragma unroll
    for (int sh = 1; sh < 64; sh <<= 1) {
        int t = __shfl_up(x, sh);
        if (lane >= sh) x += t;
    }
    if (lane == 63) wsum[w] = x;
    __syncthreads();
    int add = (w == 1) ? wsum[0] : 0;
    if (tid < NSCAN) bex[tid] = x - v + add;
}

__global__ __launch_bounds__(256) void k_scan_c(const int* __restrict__ cnt,
                                                const int* __restrict__ bex,
                                                int* __restrict__ off,
                                                int* __restrict__ cur) {
    __shared__ int swave[4];
    const int b = blockIdx.x, tid = threadIdx.x;
    const int base = b * SCAN_CHUNK + tid * 4;
    int4 v = make_int4(0, 0, 0, 0);
    if (base + 3 < N_NODES) v = *(const int4*)&cnt[base];
    else {
        if (base + 0 < N_NODES) v.x = cnt[base + 0];
        if (base + 1 < N_NODES) v.y = cnt[base + 1];
        if (base + 2 < N_NODES) v.z = cnt[base + 2];
    }
    const int tsum = v.x + v.y + v.z + v.w;
    const int lane = tid & 63, w = tid >> 6;
    int x = tsum;
    #pragma unroll
    for (int sh = 1; sh < 64; sh <<= 1) {
        int t = __shfl_up(x, sh);
        if (lane >= sh) x += t;
    }
    if (lane == 63) swave[w] = x;
    __syncthreads();
    int wadd = 0;
    for (int i = 0; i < w; i++) wadd += swave[i];
    const int ex = bex[b] + wadd + (x - tsum);
    const int p0 = ex, p1 = p0 + v.x, p2 = p1 + v.y, p3 = p2 + v.z;
    if (base + 3 < N_NODES) {
        *(int4*)&off[base] = make_int4(p0, p1, p2, p3);
        *(int4*)&cur[base] = make_int4(p0, p1, p2, p3);
    } else {
        if (base + 0 < N_NODES) { off[base + 0] = p0; cur[base + 0] = p0; }
        if (base + 1 < N_NODES) { off[base + 1] = p1; cur[base + 1] = p1; }
        if (base + 2 < N_NODES) { off[base + 2] = p2; cur[base + 2] = p2; }
    }
}

// ---------------------------------------------------------------------------
// Bucket edges by destination; (src, normalized coefficient) packed 8B.
__global__ void k_scatter(const int* __restrict__ rows, const int* __restrict__ cols,
                          const float* __restrict__ w, const float* __restrict__ dinv,
                          int* __restrict__ cursor, int2* __restrict__ sedge) {
    int e = blockIdx.x * blockDim.x + threadIdx.x;
    if (e >= N_EDGES) return;
    int r = rows[e], c = cols[e];
    float coef = dinv[r] * w[e] * dinv[c];
    int p = atomicAdd(&cursor[c], 1);
    sedge[p] = make_int2(r, __float_as_int(coef));
}

// ---------------------------------------------------------------------------
// C[n,DOUT] = A[n,128] @ W[128,DOUT]; optional fused bias+sigmoid epilogue.
template <int DOUT, bool SIG>
__global__ __launch_bounds__(256) void k_gemm(const float* __restrict__ A,
                                              const float* __restrict__ W,
                                              const float* __restrict__ bias,
                                              float* __restrict__ C) {
    constexpr int CPT = DOUT / 16;
    __shared__ float Ws[128 * DOUT];
    __shared__ float As[8][128];
    const int tid = threadIdx.x;
    const int tx = tid & 15, ty = tid >> 4;

    for (int i = tid * 4; i < 128 * DOUT; i += 256 * 4)
        *(float4*)&Ws[i] = *(const float4*)&W[i];

    const int r0 = blockIdx.x * 128;
    const int arow = tid >> 1;
    const int ak = (tid & 1) * 4;
    const bool rowok = (r0 + arow) < N_NODES;

    float acc[8][CPT];
    #pragma unroll
    for (int i = 0; i < 8; i++)
        #pragma unroll
        for (int j = 0; j < CPT; j++) acc[i][j] = 0.f;

    for (int k0 = 0; k0 < 128; k0 += 8) {
        float4 av = make_float4(0.f, 0.f, 0.f, 0.f);
        if (rowok) av = *(const float4*)&A[(size_t)(r0 + arow) * 128 + k0 + ak];
        __syncthreads();
        As[ak + 0][arow] = av.x;
        As[ak + 1][arow] = av.y;
        As[ak + 2][arow] = av.z;
        As[ak + 3][arow] = av.w;
        __syncthreads();
        #pragma unroll
        for (int kk = 0; kk < 8; kk++) {
            float4 a0 = *(const float4*)&As[kk][ty * 8];
            float4 a1 = *(const float4*)&As[kk][ty * 8 + 4];
            float av8[8] = {a0.x, a0.y, a0.z, a0.w, a1.x, a1.y, a1.z, a1.w};
            float wv[CPT];
            float4 w0 = *(const float4*)&Ws[(k0 + kk) * DOUT + tx * CPT];
            wv[0] = w0.x; wv[1] = w0.y; wv[2] = w0.z; wv[3] = w0.w;
            if constexpr (CPT == 8) {
                float4 w1 = *(const float4*)&Ws[(k0 + kk) * DOUT + tx * CPT + 4];
                wv[4] = w1.x; wv[5] = w1.y; wv[6] = w1.z; wv[7] = w1.w;
            }
            #pragma unroll
            for (int i = 0; i < 8; i++)
                #pragma unroll
                for (int j = 0; j < CPT; j++)
                    acc[i][j] = fmaf(av8[i], wv[j], acc[i][j]);
        }
    }

    #pragma unroll
    for (int i = 0; i < 8; i++) {
        int r = r0 + ty * 8 + i;
        if (r < N_NODES) {
            float vout[CPT];
            #pragma unroll
            for (int j = 0; j < CPT; j++) {
                float v = acc[i][j];
                if constexpr (SIG) {
                    v += bias[tx * CPT + j];
                    v = 1.0f / (1.0f + expf(-v));
                }
                vout[j] = v;
            }
            #pragma unroll
            for (int j = 0; j < CPT; j += 4)
                *(float4*)&C[(size_t)r * DOUT + tx * CPT + j] =
                    make_float4(vout[j], vout[j + 1], vout[j + 2], vout[j + 3]);
        }
    }
}

// ---------------------------------------------------------------------------
// Pull aggregation: one wave per destination node; lane owns 2 of 128 dims.
// 4-wide edge unroll -> 4 independent 512B gathers in flight per wave (MLP).
__global__ __launch_bounds__(256) void k_aggregate(const float* __restrict__ lin,
                                                   const int2* __restrict__ sedge,
                                                   const int* __restrict__ off,
                                                   const int* __restrict__ cnt,
                                                   const float* __restrict__ dinv,
                                                   const float* __restrict__ bias,
                                                   float* __restrict__ out) {
    const int node = (blockIdx.x * 256 + threadIdx.x) >> 6;
    const int lane = threadIdx.x & 63;
    if (node >= N_NODES) return;
    const int lane2 = lane * 2;
    const float di = dinv[node];
    const size_t base = (size_t)node * 128 + lane2;
    float2 sv = *(const float2*)&lin[base];
    float ax = di * di * sv.x;
    float ay = di * di * sv.y;
    int e = off[node];
    const int end = e + cnt[node];
    for (; e + 4 <= end; e += 4) {
        int2 e0 = sedge[e + 0];
        int2 e1 = sedge[e + 1];
        int2 e2 = sedge[e + 2];
        int2 e3 = sedge[e + 3];
        float2 v0 = *(const float2*)&lin[(size_t)e0.x * 128 + lane2];
        float2 v1 = *(const float2*)&lin[(size_t)e1.x * 128 + lane2];
        float2 v2 = *(const float2*)&lin[(size_t)e2.x * 128 + lane2];
        float2 v3 = *(const float2*)&lin[(size_t)e3.x * 128 + lane2];
        float c0 = __int_as_float(e0.y), c1 = __int_as_float(e1.y);
        float c2 = __int_as_float(e2.y), c3 = __int_as_float(e3.y);
        ax = fmaf(c0, v0.x, ax); ay = fmaf(c0, v0.y, ay);
        ax = fmaf(c1, v1.x, ax); ay = fmaf(c1, v1.y, ay);
        ax = fmaf(c2, v2.x, ax); ay = fmaf(c2, v2.y, ay);
        ax = fmaf(c3, v3.x, ax); ay = fmaf(c3, v3.y, ay);
    }
    for (; e < end; e++) {
        int2 ed = sedge[e];
        float cf = __int_as_float(ed.y);
        float2 v = *(const float2*)&lin[(size_t)ed.x * 128 + lane2];
        ax = fmaf(cf, v.x, ax);
        ay = fmaf(cf, v.y, ay);
    }
    float2 bv = *(const float2*)&bias[lane2];
    ax = fmaxf(ax + bv.x, 0.f);
    ay = fmaxf(ay + bv.y, 0.f);
    *(float2*)&out[base] = make_float2(ax, ay);
}

// ---------------------------------------------------------------------------
extern "C" void kernel_launch(void* const* d_in, const int* in_sizes, int n_in,
                              void* d_out, int out_size, void* d_ws, size_t ws_size,
                              hipStream_t stream) {
    const float* x   = (const float*)d_in[0];
    const int*   ei  = (const int*)d_in[1];
    const float* ew  = (const float*)d_in[2];
    const float* W1  = (const float*)d_in[3];
    const float* b1  = (const float*)d_in[4];
    const float* W2  = (const float*)d_in[5];
    const float* b2  = (const float*)d_in[6];
    const float* Wfc = (const float*)d_in[7];
    const float* bfc = (const float*)d_in[8];
    float* out = (float*)d_out;

    char* ws = (char*)d_ws;
    size_t o = 0;
    auto alloc = [&](size_t bytes) { char* p = ws + o; o += (bytes + 255) & ~255ull; return p; };
    float* deg   = (float*)alloc((size_t)N_NODES * 4);   // becomes dinv in-place
    int*   cnt   = (int*)  alloc((size_t)N_NODES * 4);
    int*   off   = (int*)  alloc((size_t)N_NODES * 4);
    int*   cur   = (int*)  alloc((size_t)N_NODES * 4);
    int*   flag  = (int*)  alloc(256);
    int*   bsum  = (int*)  alloc((size_t)NSCAN * 4);
    int*   bex   = (int*)  alloc((size_t)NSCAN * 4);
    int*   rows  = (int*)  alloc((size_t)N_EDGES * 4);
    int*   cols  = (int*)  alloc((size_t)N_EDGES * 4);
    int2*  sedge = (int2*) alloc((size_t)N_EDGES * 8);
    float* bufA  = (float*)alloc((size_t)N_NODES * 128 * 4);
    float* bufB  = (float*)alloc((size_t)N_NODES * 128 * 4);

    const int EB = (N_EDGES + 255) / 256;
    const int NB = (N_NODES + 255) / 256;

    int hint64 = (in_sizes[1] == 4 * N_EDGES) ? 1 : 0;
    k_detect<<<1, 256, 0, stream>>>(ei, flag, hint64);
    k_init<<<NB, 256, 0, stream>>>(deg, cnt);
    k_norm_hist<<<EB, 256, 0, stream>>>(ei, flag, ew, rows, cols, deg, cnt);
    k_dinv<<<NB, 256, 0, stream>>>(deg);
    k_scan_a<<<NSCAN, 256, 0, stream>>>(cnt, bsum);
    k_scan_b<<<1, 128, 0, stream>>>(bsum, bex);
    k_scan_c<<<NSCAN, 256, 0, stream>>>(cnt, bex, off, cur);
    k_scatter<<<EB, 256, 0, stream>>>(rows, cols, ew, deg, cur, sedge);

    const int GB = (N_NODES + 127) / 128;
    const int AB = (N_NODES * 64 + 255) / 256;

    k_gemm<128, false><<<GB, 256, 0, stream>>>(x, W1, nullptr, bufA);
    k_aggregate<<<AB, 256, 0, stream>>>(bufA, sedge, off, cnt, deg, b1, bufB);
    k_gemm<128, false><<<GB, 256, 0, stream>>>(bufB, W2, nullptr, bufA);
    k_aggregate<<<AB, 256, 0, stream>>>(bufA, sedge, off, cnt, deg, b2, bufB);
    k_gemm<64, true><<<GB, 256, 0, stream>>>(bufB, Wfc, bfc, out);
}

// Round 3
// 692.756 us; speedup vs baseline: 1.3565x; 1.0866x over previous
//
#include <hip/hip_runtime.h>
#include <math.h>

#define N_NODES 100000
#define N_EDGES 1600000
#define SCAN_CHUNK 1024
#define NSCAN ((N_NODES + SCAN_CHUNK - 1) / SCAN_CHUNK)   // 98
#define WMASK ((1ull << 40) - 1)
// D_IN = D_HID = 128, D_OUT = 64

// ---------------------------------------------------------------------------
// Edge-index dtype detection (int64 per reference vs int32 per harness doc).
// int64 buffer -> odd 32-bit words (high words) are all 0 (indices < 1e5).
__global__ void k_detect(const int* __restrict__ ei, int* __restrict__ flag, int host_hint) {
    __shared__ int s_cnt;
    if (threadIdx.x == 0) s_cnt = 0;
    __syncthreads();
    int local = 0;
    for (int e = threadIdx.x; e < 4096; e += blockDim.x)
        if (ei[2 * e + 1] != 0) local++;
    atomicAdd(&s_cnt, local);
    __syncthreads();
    if (threadIdx.x == 0) flag[0] = (host_hint || s_cnt < 100) ? 1 : 0;
}

__global__ void k_init(unsigned long long* __restrict__ packed) {
    int i = blockIdx.x * blockDim.x + threadIdx.x;
    if (i < N_NODES) packed[i] = 0ull;
}

// ---------------------------------------------------------------------------
// One packed 64-bit atomic per edge: count in [40,64), weight Q8.32 in [0,40).
// Max weighted degree << 256, max count << 2^24 -> no overflow across fields.
__global__ void k_hist(const int* __restrict__ ei32, const int* __restrict__ flag,
                       const float* __restrict__ w,
                       unsigned long long* __restrict__ packed) {
    int e = blockIdx.x * blockDim.x + threadIdx.x;
    if (e >= N_EDGES) return;
    int c;
    if (flag[0]) {
        const long long* ei64 = (const long long*)ei32;
        c = (int)ei64[N_EDGES + e];
    } else {
        c = ei32[N_EDGES + e];
    }
    unsigned long long wfix = (unsigned long long)(w[e] * 4294967296.0f);  // *2^32
    atomicAdd(&packed[c], (1ull << 40) | wfix);
}

// ---------------------------------------------------------------------------
// Scan stage A fused with unpack: packed -> cnt, dinv, per-chunk sums.
__global__ __launch_bounds__(256) void k_scan_a(const unsigned long long* __restrict__ packed,
                                                int* __restrict__ cnt,
                                                float* __restrict__ dinv,
                                                int* __restrict__ bsum) {
    __shared__ int sred[4];
    const int b = blockIdx.x, tid = threadIdx.x;
    const int base = b * SCAN_CHUNK;
    int s = 0;
    #pragma unroll
    for (int i = 0; i < 4; i++) {
        int idx = base + tid + i * 256;
        if (idx < N_NODES) {
            unsigned long long p = packed[idx];
            int c = (int)(p >> 40);
            float deg = 1.0f + (float)(p & WMASK) * 2.3283064365386963e-10f;  // 2^-32
            cnt[idx] = c;
            dinv[idx] = rsqrtf(deg);   // deg >= 1 always (self loop)
            s += c;
        }
    }
    #pragma unroll
    for (int sh = 1; sh < 64; sh <<= 1) s += __shfl_xor(s, sh);
    if ((tid & 63) == 0) sred[tid >> 6] = s;
    __syncthreads();
    if (tid == 0) bsum[b] = sred[0] + sred[1] + sred[2] + sred[3];
}

__global__ __launch_bounds__(128) void k_scan_b(const int* __restrict__ bsum,
                                                int* __restrict__ bex) {
    __shared__ int wsum[2];
    const int tid = threadIdx.x, lane = tid & 63, w = tid >> 6;
    int v = (tid < NSCAN) ? bsum[tid] : 0;
    int x = v;
    #pragma unroll
    for (int sh = 1; sh < 64; sh <<= 1) {
        int t = __shfl_up(x, sh);
        if (lane >= sh) x += t;
    }
    if (lane == 63) wsum[w] = x;
    __syncthreads();
    int add = (w == 1) ? wsum[0] : 0;
    if (tid < NSCAN) bex[tid] = x - v + add;
}

__global__ __launch_bounds__(256) void k_scan_c(const int* __restrict__ cnt,
                                                const int* __restrict__ bex,
                                                int* __restrict__ off,
                                                int* __restrict__ cur) {
    __shared__ int swave[4];
    const int b = blockIdx.x, tid = threadIdx.x;
    const int base = b * SCAN_CHUNK + tid * 4;
    int4 v = make_int4(0, 0, 0, 0);
    if (base + 3 < N_NODES) v = *(const int4*)&cnt[base];
    else {
        if (base + 0 < N_NODES) v.x = cnt[base + 0];
        if (base + 1 < N_NODES) v.y = cnt[base + 1];
        if (base + 2 < N_NODES) v.z = cnt[base + 2];
    }
    const int tsum = v.x + v.y + v.z + v.w;
    const int lane = tid & 63, w = tid >> 6;
    int x = tsum;
    #pragma unroll
    for (int sh = 1; sh < 64; sh <<= 1) {
        int t = __shfl_up(x, sh);
        if (lane >= sh) x += t;
    }
    if (lane == 63) swave[w] = x;
    __syncthreads();
    int wadd = 0;
    for (int i = 0; i < w; i++) wadd += swave[i];
    const int ex = bex[b] + wadd + (x - tsum);
    const int p0 = ex, p1 = p0 + v.x, p2 = p1 + v.y, p3 = p2 + v.z;
    if (base + 3 < N_NODES) {
        *(int4*)&off[base] = make_int4(p0, p1, p2, p3);
        *(int4*)&cur[base] = make_int4(p0, p1, p2, p3);
    } else {
        if (base + 0 < N_NODES) { off[base + 0] = p0; cur[base + 0] = p0; }
        if (base + 1 < N_NODES) { off[base + 1] = p1; cur[base + 1] = p1; }
        if (base + 2 < N_NODES) { off[base + 2] = p2; cur[base + 2] = p2; }
    }
}

// ---------------------------------------------------------------------------
// Bucket edges by destination; (src, normalized coefficient) packed 8B.
// Decodes edge_index inline (no rows/cols intermediates).
__global__ void k_scatter(const int* __restrict__ ei32, const int* __restrict__ flag,
                          const float* __restrict__ w, const float* __restrict__ dinv,
                          int* __restrict__ cursor, int2* __restrict__ sedge) {
    int e = blockIdx.x * blockDim.x + threadIdx.x;
    if (e >= N_EDGES) return;
    int r, c;
    if (flag[0]) {
        const long long* ei64 = (const long long*)ei32;
        r = (int)ei64[e];
        c = (int)ei64[N_EDGES + e];
    } else {
        r = ei32[e];
        c = ei32[N_EDGES + e];
    }
    float coef = dinv[r] * w[e] * dinv[c];
    int p = atomicAdd(&cursor[c], 1);
    sedge[p] = make_int2(r, __float_as_int(coef));
}

// ---------------------------------------------------------------------------
// C[n,DOUT] = A[n,128] @ W[128,DOUT]; optional fused bias+sigmoid epilogue.
template <int DOUT, bool SIG>
__global__ __launch_bounds__(256) void k_gemm(const float* __restrict__ A,
                                              const float* __restrict__ W,
                                              const float* __restrict__ bias,
                                              float* __restrict__ C) {
    constexpr int CPT = DOUT / 16;
    __shared__ float Ws[128 * DOUT];
    __shared__ float As[8][128];
    const int tid = threadIdx.x;
    const int tx = tid & 15, ty = tid >> 4;

    for (int i = tid * 4; i < 128 * DOUT; i += 256 * 4)
        *(float4*)&Ws[i] = *(const float4*)&W[i];

    const int r0 = blockIdx.x * 128;
    const int arow = tid >> 1;
    const int ak = (tid & 1) * 4;
    const bool rowok = (r0 + arow) < N_NODES;

    float acc[8][CPT];
    #pragma unroll
    for (int i = 0; i < 8; i++)
        #pragma unroll
        for (int j = 0; j < CPT; j++) acc[i][j] = 0.f;

    for (int k0 = 0; k0 < 128; k0 += 8) {
        float4 av = make_float4(0.f, 0.f, 0.f, 0.f);
        if (rowok) av = *(const float4*)&A[(size_t)(r0 + arow) * 128 + k0 + ak];
        __syncthreads();
        As[ak + 0][arow] = av.x;
        As[ak + 1][arow] = av.y;
        As[ak + 2][arow] = av.z;
        As[ak + 3][arow] = av.w;
        __syncthreads();
        #pragma unroll
        for (int kk = 0; kk < 8; kk++) {
            float4 a0 = *(const float4*)&As[kk][ty * 8];
            float4 a1 = *(const float4*)&As[kk][ty * 8 + 4];
            float av8[8] = {a0.x, a0.y, a0.z, a0.w, a1.x, a1.y, a1.z, a1.w};
            float wv[CPT];
            float4 w0 = *(const float4*)&Ws[(k0 + kk) * DOUT + tx * CPT];
            wv[0] = w0.x; wv[1] = w0.y; wv[2] = w0.z; wv[3] = w0.w;
            if constexpr (CPT == 8) {
                float4 w1 = *(const float4*)&Ws[(k0 + kk) * DOUT + tx * CPT + 4];
                wv[4] = w1.x; wv[5] = w1.y; wv[6] = w1.z; wv[7] = w1.w;
            }
            #pragma unroll
            for (int i = 0; i < 8; i++)
                #pragma unroll
                for (int j = 0; j < CPT; j++)
                    acc[i][j] = fmaf(av8[i], wv[j], acc[i][j]);
        }
    }

    #pragma unroll
    for (int i = 0; i < 8; i++) {
        int r = r0 + ty * 8 + i;
        if (r < N_NODES) {
            float vout[CPT];
            #pragma unroll
            for (int j = 0; j < CPT; j++) {
                float v = acc[i][j];
                if constexpr (SIG) {
                    v += bias[tx * CPT + j];
                    v = 1.0f / (1.0f + expf(-v));
                }
                vout[j] = v;
            }
            #pragma unroll
            for (int j = 0; j < CPT; j += 4)
                *(float4*)&C[(size_t)r * DOUT + tx * CPT + j] =
                    make_float4(vout[j], vout[j + 1], vout[j + 2], vout[j + 3]);
        }
    }
}

// ---------------------------------------------------------------------------
// Pull aggregation: one wave per destination node; lane owns 2 of 128 dims.
// 8-wide PREDICATED unroll: ragged tail uses clamped index + zeroed coef so
// all 8 gathers always issue in parallel (dup loads are L1-hot, coef=0).
__global__ __launch_bounds__(256) void k_aggregate(const float* __restrict__ lin,
                                                   const int2* __restrict__ sedge,
                                                   const int* __restrict__ off,
                                                   const int* __restrict__ cnt,
                                                   const float* __restrict__ dinv,
                                                   const float* __restrict__ bias,
                                                   float* __restrict__ out) {
    const int node = (blockIdx.x * 256 + threadIdx.x) >> 6;
    const int lane = threadIdx.x & 63;
    if (node >= N_NODES) return;
    const int lane2 = lane * 2;
    const float di = dinv[node];
    const size_t base = (size_t)node * 128 + lane2;
    float2 sv = *(const float2*)&lin[base];
    float ax = di * di * sv.x;
    float ay = di * di * sv.y;
    const int start = off[node];
    const int end = start + cnt[node];
    for (int e0 = start; e0 < end; e0 += 8) {
        int2 ed[8];
        #pragma unroll
        for (int i = 0; i < 8; i++) {
            int idx = e0 + i;
            ed[i] = sedge[idx < end ? idx : end - 1];
        }
        float2 v[8];
        #pragma unroll
        for (int i = 0; i < 8; i++)
            v[i] = *(const float2*)&lin[(size_t)ed[i].x * 128 + lane2];
        #pragma unroll
        for (int i = 0; i < 8; i++) {
            float cf = (e0 + i < end) ? __int_as_float(ed[i].y) : 0.0f;
            ax = fmaf(cf, v[i].x, ax);
            ay = fmaf(cf, v[i].y, ay);
        }
    }
    float2 bv = *(const float2*)&bias[lane2];
    ax = fmaxf(ax + bv.x, 0.f);
    ay = fmaxf(ay + bv.y, 0.f);
    *(float2*)&out[base] = make_float2(ax, ay);
}

// ---------------------------------------------------------------------------
extern "C" void kernel_launch(void* const* d_in, const int* in_sizes, int n_in,
                              void* d_out, int out_size, void* d_ws, size_t ws_size,
                              hipStream_t stream) {
    const float* x   = (const float*)d_in[0];
    const int*   ei  = (const int*)d_in[1];
    const float* ew  = (const float*)d_in[2];
    const float* W1  = (const float*)d_in[3];
    const float* b1  = (const float*)d_in[4];
    const float* W2  = (const float*)d_in[5];
    const float* b2  = (const float*)d_in[6];
    const float* Wfc = (const float*)d_in[7];
    const float* bfc = (const float*)d_in[8];
    float* out = (float*)d_out;

    char* ws = (char*)d_ws;
    size_t o = 0;
    auto alloc = [&](size_t bytes) { char* p = ws + o; o += (bytes + 255) & ~255ull; return p; };
    unsigned long long* packed = (unsigned long long*)alloc((size_t)N_NODES * 8);
    float* dinv  = (float*)alloc((size_t)N_NODES * 4);
    int*   cnt   = (int*)  alloc((size_t)N_NODES * 4);
    int*   off   = (int*)  alloc((size_t)N_NODES * 4);
    int*   cur   = (int*)  alloc((size_t)N_NODES * 4);
    int*   flag  = (int*)  alloc(256);
    int*   bsum  = (int*)  alloc((size_t)NSCAN * 4);
    int*   bex   = (int*)  alloc((size_t)NSCAN * 4);
    int2*  sedge = (int2*) alloc((size_t)N_EDGES * 8);
    float* bufA  = (float*)alloc((size_t)N_NODES * 128 * 4);
    float* bufB  = (float*)alloc((size_t)N_NODES * 128 * 4);

    const int EB = (N_EDGES + 255) / 256;
    const int NB = (N_NODES + 255) / 256;

    int hint64 = (in_sizes[1] == 4 * N_EDGES) ? 1 : 0;
    k_detect<<<1, 256, 0, stream>>>(ei, flag, hint64);
    k_init<<<NB, 256, 0, stream>>>(packed);
    k_hist<<<EB, 256, 0, stream>>>(ei, flag, ew, packed);
    k_scan_a<<<NSCAN, 256, 0, stream>>>(packed, cnt, dinv, bsum);
    k_scan_b<<<1, 128, 0, stream>>>(bsum, bex);
    k_scan_c<<<NSCAN, 256, 0, stream>>>(cnt, bex, off, cur);
    k_scatter<<<EB, 256, 0, stream>>>(ei, flag, ew, dinv, cur, sedge);

    const int GB = (N_NODES + 127) / 128;
    const int AB = (N_NODES * 64 + 255) / 256;

    k_gemm<128, false><<<GB, 256, 0, stream>>>(x, W1, nullptr, bufA);
    k_aggregate<<<AB, 256, 0, stream>>>(bufA, sedge, off, cnt, dinv, b1, bufB);
    k_gemm<128, false><<<GB, 256, 0, stream>>>(bufB, W2, nullptr, bufA);
    k_aggregate<<<AB, 256, 0, stream>>>(bufA, sedge, off, cnt, dinv, b2, bufB);
    k_gemm<64, true><<<GB, 256, 0, stream>>>(bufB, Wfc, bfc, out);
}

// Round 5
// 563.366 us; speedup vs baseline: 1.6680x; 1.2297x over previous
//
#include <hip/hip_runtime.h>
#include <math.h>

#define N_NODES 100000
#define N_EDGES 1600000
#define SCAN_CHUNK 1024
#define NSCAN ((N_NODES + SCAN_CHUNK - 1) / SCAN_CHUNK)   // 98
#define WMASK ((1ull << 40) - 1)
// D_IN = D_HID = 128, D_OUT = 64

// ---------------------------------------------------------------------------
// bf16x2 <-> f32 helpers (packed in a uint; low 16 = even dim, high = odd dim)
__device__ __forceinline__ float2 bf2f(unsigned int u) {
    float2 r;
    r.x = __uint_as_float(u << 16);
    r.y = __uint_as_float(u & 0xffff0000u);
    return r;
}
__device__ __forceinline__ unsigned int f2bf2(float a, float b) {
    unsigned int ua = __float_as_uint(a), ub = __float_as_uint(b);
    ua += 0x7fffu + ((ua >> 16) & 1u);          // RNE
    ub += 0x7fffu + ((ub >> 16) & 1u);
    return (ua >> 16) | (ub & 0xffff0000u);
}

// ---------------------------------------------------------------------------
// Edge-index dtype detection (int64 per reference vs int32 per harness doc).
__global__ void k_detect(const int* __restrict__ ei, int* __restrict__ flag, int host_hint) {
    __shared__ int s_cnt;
    if (threadIdx.x == 0) s_cnt = 0;
    __syncthreads();
    int local = 0;
    for (int e = threadIdx.x; e < 4096; e += blockDim.x)
        if (ei[2 * e + 1] != 0) local++;
    atomicAdd(&s_cnt, local);
    __syncthreads();
    if (threadIdx.x == 0) flag[0] = (host_hint || s_cnt < 100) ? 1 : 0;
}

__global__ void k_init(unsigned long long* __restrict__ packed) {
    int i = blockIdx.x * blockDim.x + threadIdx.x;
    if (i < N_NODES) packed[i] = 0ull;
}

// One packed 64-bit atomic per edge: count in [40,64), weight Q8.32 in [0,40).
__global__ void k_hist(const int* __restrict__ ei32, const int* __restrict__ flag,
                       const float* __restrict__ w,
                       unsigned long long* __restrict__ packed) {
    int e = blockIdx.x * blockDim.x + threadIdx.x;
    if (e >= N_EDGES) return;
    int c;
    if (flag[0]) {
        const long long* ei64 = (const long long*)ei32;
        c = (int)ei64[N_EDGES + e];
    } else {
        c = ei32[N_EDGES + e];
    }
    unsigned long long wfix = (unsigned long long)(w[e] * 4294967296.0f);  // *2^32
    atomicAdd(&packed[c], (1ull << 40) | wfix);
}

// ---------------------------------------------------------------------------
// Scan stage A fused with unpack: packed -> cnt, dinv, per-chunk sums.
__global__ __launch_bounds__(256) void k_scan_a(const unsigned long long* __restrict__ packed,
                                                int* __restrict__ cnt,
                                                float* __restrict__ dinv,
                                                int* __restrict__ bsum) {
    __shared__ int sred[4];
    const int b = blockIdx.x, tid = threadIdx.x;
    const int base = b * SCAN_CHUNK;
    int s = 0;
    #pragma unroll
    for (int i = 0; i < 4; i++) {
        int idx = base + tid + i * 256;
        if (idx < N_NODES) {
            unsigned long long p = packed[idx];
            int c = (int)(p >> 40);
            float deg = 1.0f + (float)(p & WMASK) * 2.3283064365386963e-10f;  // 2^-32
            cnt[idx] = c;
            dinv[idx] = rsqrtf(deg);   // deg >= 1 always (self loop)
            s += c;
        }
    }
    #pragma unroll
    for (int sh = 1; sh < 64; sh <<= 1) s += __shfl_xor(s, sh);
    if ((tid & 63) == 0) sred[tid >> 6] = s;
    __syncthreads();
    if (tid == 0) bsum[b] = sred[0] + sred[1] + sred[2] + sred[3];
}

__global__ __launch_bounds__(128) void k_scan_b(const int* __restrict__ bsum,
                                                int* __restrict__ bex) {
    __shared__ int wsum[2];
    const int tid = threadIdx.x, lane = tid & 63, w = tid >> 6;
    int v = (tid < NSCAN) ? bsum[tid] : 0;
    int x = v;
    #pragma unroll
    for (int sh = 1; sh < 64; sh <<= 1) {
        int t = __shfl_up(x, sh);
        if (lane >= sh) x += t;
    }
    if (lane == 63) wsum[w] = x;
    __syncthreads();
    int add = (w == 1) ? wsum[0] : 0;
    if (tid < NSCAN) bex[tid] = x - v + add;
}

__global__ __launch_bounds__(256) void k_scan_c(const int* __restrict__ cnt,
                                                const int* __restrict__ bex,
                                                int* __restrict__ off,
                                                int* __restrict__ cur) {
    __shared__ int swave[4];
    const int b = blockIdx.x, tid = threadIdx.x;
    const int base = b * SCAN_CHUNK + tid * 4;
    int4 v = make_int4(0, 0, 0, 0);
    if (base + 3 < N_NODES) v = *(const int4*)&cnt[base];
    else {
        if (base + 0 < N_NODES) v.x = cnt[base + 0];
        if (base + 1 < N_NODES) v.y = cnt[base + 1];
        if (base + 2 < N_NODES) v.z = cnt[base + 2];
    }
    const int tsum = v.x + v.y + v.z + v.w;
    const int lane = tid & 63, w = tid >> 6;
    int x = tsum;
    #pragma unroll
    for (int sh = 1; sh < 64; sh <<= 1) {
        int t = __shfl_up(x, sh);
        if (lane >= sh) x += t;
    }
    if (lane == 63) swave[w] = x;
    __syncthreads();
    int wadd = 0;
    for (int i = 0; i < w; i++) wadd += swave[i];
    const int ex = bex[b] + wadd + (x - tsum);
    const int p0 = ex, p1 = p0 + v.x, p2 = p1 + v.y, p3 = p2 + v.z;
    if (base + 3 < N_NODES) {
        *(int4*)&off[base] = make_int4(p0, p1, p2, p3);
        *(int4*)&cur[base] = make_int4(p0, p1, p2, p3);
    } else {
        if (base + 0 < N_NODES) { off[base + 0] = p0; cur[base + 0] = p0; }
        if (base + 1 < N_NODES) { off[base + 1] = p1; cur[base + 1] = p1; }
        if (base + 2 < N_NODES) { off[base + 2] = p2; cur[base + 2] = p2; }
    }
}

// ---------------------------------------------------------------------------
// Bucket edges by destination; 4-byte entry: (src << 15) | Q0.15 coefficient.
// coef = dinv[r]*w*dinv[c] < 1 always (deg >= 1, w in [0,1)).
__global__ void k_scatter(const int* __restrict__ ei32, const int* __restrict__ flag,
                          const float* __restrict__ w, const float* __restrict__ dinv,
                          int* __restrict__ cursor, unsigned int* __restrict__ sedge) {
    int e = blockIdx.x * blockDim.x + threadIdx.x;
    if (e >= N_EDGES) return;
    int r, c;
    if (flag[0]) {
        const long long* ei64 = (const long long*)ei32;
        r = (int)ei64[e];
        c = (int)ei64[N_EDGES + e];
    } else {
        r = ei32[e];
        c = ei32[N_EDGES + e];
    }
    float coef = dinv[r] * w[e] * dinv[c];
    unsigned int q = (unsigned int)(coef * 32767.0f + 0.5f);
    int p = atomicAdd(&cursor[c], 1);
    sedge[p] = ((unsigned int)r << 15) | q;
}

// ---------------------------------------------------------------------------
// C[n,DOUT] = A[n,128] @ W[128,DOUT].
// OBF16: write packed bf16 rows (uint stride 64). SIG: bias+sigmoid fp32 out.
template <int DOUT, bool SIG, bool OBF16>
__global__ __launch_bounds__(256) void k_gemm(const float* __restrict__ A,
                                              const float* __restrict__ W,
                                              const float* __restrict__ bias,
                                              void* __restrict__ Cv) {
    constexpr int CPT = DOUT / 16;
    __shared__ float Ws[128 * DOUT];
    __shared__ float As[8][128];
    const int tid = threadIdx.x;
    const int tx = tid & 15, ty = tid >> 4;

    for (int i = tid * 4; i < 128 * DOUT; i += 256 * 4)
        *(float4*)&Ws[i] = *(const float4*)&W[i];

    const int r0 = blockIdx.x * 128;
    const int arow = tid >> 1;
    const int ak = (tid & 1) * 4;
    const bool rowok = (r0 + arow) < N_NODES;

    float acc[8][CPT];
    #pragma unroll
    for (int i = 0; i < 8; i++)
        #pragma unroll
        for (int j = 0; j < CPT; j++) acc[i][j] = 0.f;

    for (int k0 = 0; k0 < 128; k0 += 8) {
        float4 av = make_float4(0.f, 0.f, 0.f, 0.f);
        if (rowok) av = *(const float4*)&A[(size_t)(r0 + arow) * 128 + k0 + ak];
        __syncthreads();
        As[ak + 0][arow] = av.x;
        As[ak + 1][arow] = av.y;
        As[ak + 2][arow] = av.z;
        As[ak + 3][arow] = av.w;
        __syncthreads();
        #pragma unroll
        for (int kk = 0; kk < 8; kk++) {
            float4 a0 = *(const float4*)&As[kk][ty * 8];
            float4 a1 = *(const float4*)&As[kk][ty * 8 + 4];
            float av8[8] = {a0.x, a0.y, a0.z, a0.w, a1.x, a1.y, a1.z, a1.w};
            float wv[CPT];
            float4 w0 = *(const float4*)&Ws[(k0 + kk) * DOUT + tx * CPT];
            wv[0] = w0.x; wv[1] = w0.y; wv[2] = w0.z; wv[3] = w0.w;
            if constexpr (CPT == 8) {
                float4 w1 = *(const float4*)&Ws[(k0 + kk) * DOUT + tx * CPT + 4];
                wv[4] = w1.x; wv[5] = w1.y; wv[6] = w1.z; wv[7] = w1.w;
            }
            #pragma unroll
            for (int i = 0; i < 8; i++)
                #pragma unroll
                for (int j = 0; j < CPT; j++)
                    acc[i][j] = fmaf(av8[i], wv[j], acc[i][j]);
        }
    }

    #pragma unroll
    for (int i = 0; i < 8; i++) {
        int r = r0 + ty * 8 + i;
        if (r < N_NODES) {
            if constexpr (OBF16) {
                unsigned int* Cb = (unsigned int*)Cv;
                uint4 pk;
                pk.x = f2bf2(acc[i][0], acc[i][1]);
                pk.y = f2bf2(acc[i][2], acc[i][3]);
                pk.z = f2bf2(acc[i][4], acc[i][5]);
                pk.w = f2bf2(acc[i][6], acc[i][7]);
                *(uint4*)&Cb[(size_t)r * 64 + tx * 4] = pk;
            } else {
                float* C = (float*)Cv;
                float vout[CPT];
                #pragma unroll
                for (int j = 0; j < CPT; j++) {
                    float v = acc[i][j];
                    if constexpr (SIG) {
                        v += bias[tx * CPT + j];
                        v = 1.0f / (1.0f + expf(-v));
                    }
                    vout[j] = v;
                }
                #pragma unroll
                for (int j = 0; j < CPT; j += 4)
                    *(float4*)&C[(size_t)r * DOUT + tx * CPT + j] =
                        make_float4(vout[j], vout[j + 1], vout[j + 2], vout[j + 3]);
            }
        }
    }
}

// ---------------------------------------------------------------------------
// Pull aggregation over bf16 rows: one wave per node; lane owns 2 of 128 dims
// (one packed uint). 8-wide predicated unroll; fp32 accumulate; fp32 output.
__global__ __launch_bounds__(256) void k_aggregate(const unsigned int* __restrict__ lin,
                                                   const unsigned int* __restrict__ sedge,
                                                   const int* __restrict__ off,
                                                   const int* __restrict__ cnt,
                                                   const float* __restrict__ dinv,
                                                   const float* __restrict__ bias,
                                                   float* __restrict__ out) {
    const int node = (blockIdx.x * 256 + threadIdx.x) >> 6;
    const int lane = threadIdx.x & 63;
    if (node >= N_NODES) return;
    const float di = dinv[node];
    float2 sv = bf2f(lin[(size_t)node * 64 + lane]);
    float ax = di * di * sv.x;
    float ay = di * di * sv.y;
    const int start = __builtin_amdgcn_readfirstlane(off[node]);
    const int end = start + __builtin_amdgcn_readfirstlane(cnt[node]);
    for (int e0 = start; e0 < end; e0 += 8) {
        unsigned int en[8];
        #pragma unroll
        for (int i = 0; i < 8; i++) {
            int idx = e0 + i;
            en[i] = sedge[idx < end ? idx : end - 1];
        }
        float2 v[8];
        #pragma unroll
        for (int i = 0; i < 8; i++)
            v[i] = bf2f(lin[(size_t)(en[i] >> 15) * 64 + lane]);
        #pragma unroll
        for (int i = 0; i < 8; i++) {
            float cf = (e0 + i < end) ? (float)(en[i] & 0x7fffu) * 3.051850947599719e-05f : 0.0f;
            ax = fmaf(cf, v[i].x, ax);
            ay = fmaf(cf, v[i].y, ay);
        }
    }
    const int lane2 = lane * 2;
    float2 bv = *(const float2*)&bias[lane2];
    ax = fmaxf(ax + bv.x, 0.f);
    ay = fmaxf(ay + bv.y, 0.f);
    *(float2*)&out[(size_t)node * 128 + lane2] = make_float2(ax, ay);
}

// ---------------------------------------------------------------------------
extern "C" void kernel_launch(void* const* d_in, const int* in_sizes, int n_in,
                              void* d_out, int out_size, void* d_ws, size_t ws_size,
                              hipStream_t stream) {
    const float* x   = (const float*)d_in[0];
    const int*   ei  = (const int*)d_in[1];
    const float* ew  = (const float*)d_in[2];
    const float* W1  = (const float*)d_in[3];
    const float* b1  = (const float*)d_in[4];
    const float* W2  = (const float*)d_in[5];
    const float* b2  = (const float*)d_in[6];
    const float* Wfc = (const float*)d_in[7];
    const float* bfc = (const float*)d_in[8];
    float* out = (float*)d_out;

    char* ws = (char*)d_ws;
    size_t o = 0;
    auto alloc = [&](size_t bytes) { char* p = ws + o; o += (bytes + 255) & ~255ull; return p; };
    unsigned long long* packed = (unsigned long long*)alloc((size_t)N_NODES * 8);
    float* dinv  = (float*)alloc((size_t)N_NODES * 4);
    int*   cnt   = (int*)  alloc((size_t)N_NODES * 4);
    int*   off   = (int*)  alloc((size_t)N_NODES * 4);
    int*   cur   = (int*)  alloc((size_t)N_NODES * 4);
    int*   flag  = (int*)  alloc(256);
    int*   bsum  = (int*)  alloc((size_t)NSCAN * 4);
    int*   bex   = (int*)  alloc((size_t)NSCAN * 4);
    unsigned int* sedge = (unsigned int*)alloc((size_t)N_EDGES * 4);
    unsigned int* hbf   = (unsigned int*)alloc((size_t)N_NODES * 64 * 4);  // bf16 rows
    float*        aggf  = (float*)alloc((size_t)N_NODES * 128 * 4);        // fp32 agg out

    const int EB = (N_EDGES + 255) / 256;
    const int NB = (N_NODES + 255) / 256;

    int hint64 = (in_sizes[1] == 4 * N_EDGES) ? 1 : 0;
    k_detect<<<1, 256, 0, stream>>>(ei, flag, hint64);
    k_init<<<NB, 256, 0, stream>>>(packed);
    k_hist<<<EB, 256, 0, stream>>>(ei, flag, ew, packed);
    k_scan_a<<<NSCAN, 256, 0, stream>>>(packed, cnt, dinv, bsum);
    k_scan_b<<<1, 128, 0, stream>>>(bsum, bex);
    k_scan_c<<<NSCAN, 256, 0, stream>>>(cnt, bex, off, cur);
    k_scatter<<<EB, 256, 0, stream>>>(ei, flag, ew, dinv, cur, sedge);

    const int GB = (N_NODES + 127) / 128;
    const int AB = (N_NODES * 64 + 255) / 256;   // 1 wave per node

    k_gemm<128, false, true><<<GB, 256, 0, stream>>>(x, W1, nullptr, hbf);
    k_aggregate<<<AB, 256, 0, stream>>>(hbf, sedge, off, cnt, dinv, b1, aggf);
    k_gemm<128, false, true><<<GB, 256, 0, stream>>>(aggf, W2, nullptr, hbf);
    k_aggregate<<<AB, 256, 0, stream>>>(hbf, sedge, off, cnt, dinv, b2, aggf);
    k_gemm<64, true, false><<<GB, 256, 0, stream>>>(aggf, Wfc, bfc, out);
}

// Round 6
// 480.654 us; speedup vs baseline: 1.9551x; 1.1721x over previous
//
#include <hip/hip_runtime.h>
#include <math.h>

#define N_NODES 100000
#define N_EDGES 1600000
#define SCAN_CHUNK 1024
#define NSCAN ((N_NODES + SCAN_CHUNK - 1) / SCAN_CHUNK)   // 98
#define WMASK ((1ull << 40) - 1)
#define LDSW 136   // LDS row stride in shorts: 272B, 16B-aligned, bank-spread
// D_IN = D_HID = 128, D_OUT = 64

typedef short bf16x8 __attribute__((ext_vector_type(8)));
typedef float f32x4 __attribute__((ext_vector_type(4)));

// ---------------------------------------------------------------------------
// bf16 helpers (packed uint: low 16 = even dim, high = odd dim; RNE casts)
__device__ __forceinline__ float2 bf2f(unsigned int u) {
    float2 r;
    r.x = __uint_as_float(u << 16);
    r.y = __uint_as_float(u & 0xffff0000u);
    return r;
}
__device__ __forceinline__ unsigned int f2bf2(float a, float b) {
    unsigned int ua = __float_as_uint(a), ub = __float_as_uint(b);
    ua += 0x7fffu + ((ua >> 16) & 1u);
    ub += 0x7fffu + ((ub >> 16) & 1u);
    return (ua >> 16) | (ub & 0xffff0000u);
}
__device__ __forceinline__ unsigned short f2bf(float a) {
    unsigned int u = __float_as_uint(a);
    u += 0x7fffu + ((u >> 16) & 1u);
    return (unsigned short)(u >> 16);
}

// ---------------------------------------------------------------------------
// Edge-index dtype detection (int64 per reference vs int32 per harness doc).
__global__ void k_detect(const int* __restrict__ ei, int* __restrict__ flag, int host_hint) {
    __shared__ int s_cnt;
    if (threadIdx.x == 0) s_cnt = 0;
    __syncthreads();
    int local = 0;
    for (int e = threadIdx.x; e < 4096; e += blockDim.x)
        if (ei[2 * e + 1] != 0) local++;
    atomicAdd(&s_cnt, local);
    __syncthreads();
    if (threadIdx.x == 0) flag[0] = (host_hint || s_cnt < 100) ? 1 : 0;
}

__global__ void k_init(unsigned long long* __restrict__ packed) {
    int i = blockIdx.x * blockDim.x + threadIdx.x;
    if (i < N_NODES) packed[i] = 0ull;
}

// One packed 64-bit atomic per edge: count in [40,64), weight Q8.32 in [0,40).
__global__ void k_hist(const int* __restrict__ ei32, const int* __restrict__ flag,
                       const float* __restrict__ w,
                       unsigned long long* __restrict__ packed) {
    int e = blockIdx.x * blockDim.x + threadIdx.x;
    if (e >= N_EDGES) return;
    int c;
    if (flag[0]) {
        const long long* ei64 = (const long long*)ei32;
        c = (int)ei64[N_EDGES + e];
    } else {
        c = ei32[N_EDGES + e];
    }
    unsigned long long wfix = (unsigned long long)(w[e] * 4294967296.0f);  // *2^32
    atomicAdd(&packed[c], (1ull << 40) | wfix);
}

// ---------------------------------------------------------------------------
// Scan stage A fused with unpack: packed -> cnt, dinv, per-chunk sums.
__global__ __launch_bounds__(256) void k_scan_a(const unsigned long long* __restrict__ packed,
                                                int* __restrict__ cnt,
                                                float* __restrict__ dinv,
                                                int* __restrict__ bsum) {
    __shared__ int sred[4];
    const int b = blockIdx.x, tid = threadIdx.x;
    const int base = b * SCAN_CHUNK;
    int s = 0;
    #pragma unroll
    for (int i = 0; i < 4; i++) {
        int idx = base + tid + i * 256;
        if (idx < N_NODES) {
            unsigned long long p = packed[idx];
            int c = (int)(p >> 40);
            float deg = 1.0f + (float)(p & WMASK) * 2.3283064365386963e-10f;  // 2^-32
            cnt[idx] = c;
            dinv[idx] = rsqrtf(deg);   // deg >= 1 always (self loop)
            s += c;
        }
    }
    #pragma unroll
    for (int sh = 1; sh < 64; sh <<= 1) s += __shfl_xor(s, sh);
    if ((tid & 63) == 0) sred[tid >> 6] = s;
    __syncthreads();
    if (tid == 0) bsum[b] = sred[0] + sred[1] + sred[2] + sred[3];
}

__global__ __launch_bounds__(128) void k_scan_b(const int* __restrict__ bsum,
                                                int* __restrict__ bex) {
    __shared__ int wsum[2];
    const int tid = threadIdx.x, lane = tid & 63, w = tid >> 6;
    int v = (tid < NSCAN) ? bsum[tid] : 0;
    int x = v;
    #pragma unroll
    for (int sh = 1; sh < 64; sh <<= 1) {
        int t = __shfl_up(x, sh);
        if (lane >= sh) x += t;
    }
    if (lane == 63) wsum[w] = x;
    __syncthreads();
    int add = (w == 1) ? wsum[0] : 0;
    if (tid < NSCAN) bex[tid] = x - v + add;
}

__global__ __launch_bounds__(256) void k_scan_c(const int* __restrict__ cnt,
                                                const int* __restrict__ bex,
                                                int* __restrict__ off,
                                                int* __restrict__ cur) {
    __shared__ int swave[4];
    const int b = blockIdx.x, tid = threadIdx.x;
    const int base = b * SCAN_CHUNK + tid * 4;
    int4 v = make_int4(0, 0, 0, 0);
    if (base + 3 < N_NODES) v = *(const int4*)&cnt[base];
    else {
        if (base + 0 < N_NODES) v.x = cnt[base + 0];
        if (base + 1 < N_NODES) v.y = cnt[base + 1];
        if (base + 2 < N_NODES) v.z = cnt[base + 2];
    }
    const int tsum = v.x + v.y + v.z + v.w;
    const int lane = tid & 63, w = tid >> 6;
    int x = tsum;
    #pragma unroll
    for (int sh = 1; sh < 64; sh <<= 1) {
        int t = __shfl_up(x, sh);
        if (lane >= sh) x += t;
    }
    if (lane == 63) swave[w] = x;
    __syncthreads();
    int wadd = 0;
    for (int i = 0; i < w; i++) wadd += swave[i];
    const int ex = bex[b] + wadd + (x - tsum);
    const int p0 = ex, p1 = p0 + v.x, p2 = p1 + v.y, p3 = p2 + v.z;
    if (base + 3 < N_NODES) {
        *(int4*)&off[base] = make_int4(p0, p1, p2, p3);
        *(int4*)&cur[base] = make_int4(p0, p1, p2, p3);
    } else {
        if (base + 0 < N_NODES) { off[base + 0] = p0; cur[base + 0] = p0; }
        if (base + 1 < N_NODES) { off[base + 1] = p1; cur[base + 1] = p1; }
        if (base + 2 < N_NODES) { off[base + 2] = p2; cur[base + 2] = p2; }
    }
}

// ---------------------------------------------------------------------------
// Bucket edges by destination; 4-byte entry: (src << 15) | Q0.15 coefficient.
__global__ void k_scatter(const int* __restrict__ ei32, const int* __restrict__ flag,
                          const float* __restrict__ w, const float* __restrict__ dinv,
                          int* __restrict__ cursor, unsigned int* __restrict__ sedge) {
    int e = blockIdx.x * blockDim.x + threadIdx.x;
    if (e >= N_EDGES) return;
    int r, c;
    if (flag[0]) {
        const long long* ei64 = (const long long*)ei32;
        r = (int)ei64[e];
        c = (int)ei64[N_EDGES + e];
    } else {
        r = ei32[e];
        c = ei32[N_EDGES + e];
    }
    float coef = dinv[r] * w[e] * dinv[c];
    unsigned int q = (unsigned int)(coef * 32767.0f + 0.5f);
    int p = atomicAdd(&cursor[c], 1);
    sedge[p] = ((unsigned int)r << 15) | q;
}

// ---------------------------------------------------------------------------
// W[128][128] f32 -> Wt[n][k] bf16 (transposed so B-fragments are contiguous).
__global__ void k_castw(const float* __restrict__ W, unsigned short* __restrict__ Wt) {
    int i = blockIdx.x * blockDim.x + threadIdx.x;   // 16384
    int k = i >> 7, n = i & 127;
    Wt[n * 128 + k] = f2bf(W[k * 128 + n]);
}

// ---------------------------------------------------------------------------
// MFMA GEMM: C[n,128] = A[n,128] @ W[128,128], bf16 inputs, f32 accum,
// bf16 packed output rows. Block = 128 rows x 128 cols, 4 waves.
// Fragment layouts (guide-verified m89/m91): A: row=lane&15, k=(lane>>4)*8+i;
// B: col=lane&15, k=(lane>>4)*8+i; D: col=lane&15, row=(lane>>4)*4+reg.
template <bool ABF16>
__global__ __launch_bounds__(256) void k_gemm_mfma(const void* __restrict__ Av,
                                                   const unsigned short* __restrict__ Wt,
                                                   unsigned short* __restrict__ Cb) {
    __shared__ unsigned short Al[128 * LDSW];
    __shared__ unsigned short Wl[128 * LDSW];
    const int tid = threadIdx.x;
    const int srow = tid >> 1, h = tid & 1;      // staging: row, 64-short half
    const int r0 = blockIdx.x * 128;

    // stage Wt[n][k] -> Wl
    {
        const uint4* src = (const uint4*)&Wt[srow * 128 + h * 64];
        uint4* dst = (uint4*)&Wl[srow * LDSW + h * 64];
        #pragma unroll
        for (int c = 0; c < 8; c++) dst[c] = src[c];
    }
    // stage A rows -> Al (cast f32->bf16 on the fly for layer 1)
    {
        const bool ok = (r0 + srow) < N_NODES;
        uint4* dst = (uint4*)&Al[srow * LDSW + h * 64];
        if constexpr (ABF16) {
            const uint4* src = (const uint4*)((const unsigned short*)Av +
                                              (size_t)(r0 + srow) * 128 + h * 64);
            uint4 z = make_uint4(0, 0, 0, 0);
            #pragma unroll
            for (int c = 0; c < 8; c++) dst[c] = ok ? src[c] : z;
        } else {
            const float* src = (const float*)Av + (size_t)(r0 + srow) * 128 + h * 64;
            #pragma unroll
            for (int c = 0; c < 8; c++) {
                float4 f0 = ok ? *(const float4*)&src[c * 8]     : make_float4(0, 0, 0, 0);
                float4 f1 = ok ? *(const float4*)&src[c * 8 + 4] : make_float4(0, 0, 0, 0);
                uint4 pk;
                pk.x = f2bf2(f0.x, f0.y);
                pk.y = f2bf2(f0.z, f0.w);
                pk.z = f2bf2(f1.x, f1.y);
                pk.w = f2bf2(f1.z, f1.w);
                dst[c] = pk;
            }
        }
    }
    __syncthreads();

    const int lane = tid & 63;
    const int w = tid >> 6;          // wave -> rows [w*32, w*32+32)
    const int lr = lane & 15;
    const int kg = lane >> 4;        // k-group
    f32x4 acc[2][8] = {};

    #pragma unroll
    for (int k0 = 0; k0 < 128; k0 += 32) {
        const int kb = k0 + kg * 8;
        bf16x8 a0 = *(const bf16x8*)&Al[(w * 32 + lr) * LDSW + kb];
        bf16x8 a1 = *(const bf16x8*)&Al[(w * 32 + 16 + lr) * LDSW + kb];
        #pragma unroll
        for (int ct = 0; ct < 8; ct++) {
            bf16x8 b = *(const bf16x8*)&Wl[(ct * 16 + lr) * LDSW + kb];
            acc[0][ct] = __builtin_amdgcn_mfma_f32_16x16x32_bf16(a0, b, acc[0][ct], 0, 0, 0);
            acc[1][ct] = __builtin_amdgcn_mfma_f32_16x16x32_bf16(a1, b, acc[1][ct], 0, 0, 0);
        }
    }

    #pragma unroll
    for (int rt = 0; rt < 2; rt++)
        #pragma unroll
        for (int r = 0; r < 4; r++) {
            int row = r0 + w * 32 + rt * 16 + kg * 4 + r;
            if (row < N_NODES) {
                #pragma unroll
                for (int ct = 0; ct < 8; ct++)
                    Cb[(size_t)row * 128 + ct * 16 + lr] = f2bf(acc[rt][ct][r]);
            }
        }
}

// ---------------------------------------------------------------------------
// Vector-f32 GEMM for the fc head: C[n,64] = A[n,128] @ Wfc + bias, sigmoid.
template <int DOUT>
__global__ __launch_bounds__(256) void k_gemm(const float* __restrict__ A,
                                              const float* __restrict__ W,
                                              const float* __restrict__ bias,
                                              float* __restrict__ C) {
    constexpr int CPT = DOUT / 16;
    __shared__ float Ws[128 * DOUT];
    __shared__ float As[8][128];
    const int tid = threadIdx.x;
    const int tx = tid & 15, ty = tid >> 4;

    for (int i = tid * 4; i < 128 * DOUT; i += 256 * 4)
        *(float4*)&Ws[i] = *(const float4*)&W[i];

    const int r0 = blockIdx.x * 128;
    const int arow = tid >> 1;
    const int ak = (tid & 1) * 4;
    const bool rowok = (r0 + arow) < N_NODES;

    float acc[8][CPT];
    #pragma unroll
    for (int i = 0; i < 8; i++)
        #pragma unroll
        for (int j = 0; j < CPT; j++) acc[i][j] = 0.f;

    for (int k0 = 0; k0 < 128; k0 += 8) {
        float4 av = make_float4(0.f, 0.f, 0.f, 0.f);
        if (rowok) av = *(const float4*)&A[(size_t)(r0 + arow) * 128 + k0 + ak];
        __syncthreads();
        As[ak + 0][arow] = av.x;
        As[ak + 1][arow] = av.y;
        As[ak + 2][arow] = av.z;
        As[ak + 3][arow] = av.w;
        __syncthreads();
        #pragma unroll
        for (int kk = 0; kk < 8; kk++) {
            float4 a0 = *(const float4*)&As[kk][ty * 8];
            float4 a1 = *(const float4*)&As[kk][ty * 8 + 4];
            float av8[8] = {a0.x, a0.y, a0.z, a0.w, a1.x, a1.y, a1.z, a1.w};
            float wv[CPT];
            float4 w0 = *(const float4*)&Ws[(k0 + kk) * DOUT + tx * CPT];
            wv[0] = w0.x; wv[1] = w0.y; wv[2] = w0.z; wv[3] = w0.w;
            #pragma unroll
            for (int i = 0; i < 8; i++)
                #pragma unroll
                for (int j = 0; j < CPT; j++)
                    acc[i][j] = fmaf(av8[i], wv[j], acc[i][j]);
        }
    }

    #pragma unroll
    for (int i = 0; i < 8; i++) {
        int r = r0 + ty * 8 + i;
        if (r < N_NODES) {
            float vout[CPT];
            #pragma unroll
            for (int j = 0; j < CPT; j++) {
                float v = acc[i][j] + bias[tx * CPT + j];
                vout[j] = 1.0f / (1.0f + expf(-v));
            }
            #pragma unroll
            for (int j = 0; j < CPT; j += 4)
                *(float4*)&C[(size_t)r * DOUT + tx * CPT + j] =
                    make_float4(vout[j], vout[j + 1], vout[j + 2], vout[j + 3]);
        }
    }
}

// ---------------------------------------------------------------------------
// Pull aggregation over bf16 rows; OBF16 selects bf16-packed vs f32 output.
template <bool OBF16>
__global__ __launch_bounds__(256) void k_aggregate(const unsigned int* __restrict__ lin,
                                                   const unsigned int* __restrict__ sedge,
                                                   const int* __restrict__ off,
                                                   const int* __restrict__ cnt,
                                                   const float* __restrict__ dinv,
                                                   const float* __restrict__ bias,
                                                   void* __restrict__ outv) {
    const int node = (blockIdx.x * 256 + threadIdx.x) >> 6;
    const int lane = threadIdx.x & 63;
    if (node >= N_NODES) return;
    const float di = dinv[node];
    float2 sv = bf2f(lin[(size_t)node * 64 + lane]);
    float ax = di * di * sv.x;
    float ay = di * di * sv.y;
    const int start = __builtin_amdgcn_readfirstlane(off[node]);
    const int end = start + __builtin_amdgcn_readfirstlane(cnt[node]);
    for (int e0 = start; e0 < end; e0 += 8) {
        unsigned int en[8];
        #pragma unroll
        for (int i = 0; i < 8; i++) {
            int idx = e0 + i;
            en[i] = sedge[idx < end ? idx : end - 1];
        }
        float2 v[8];
        #pragma unroll
        for (int i = 0; i < 8; i++)
            v[i] = bf2f(lin[(size_t)(en[i] >> 15) * 64 + lane]);
        #pragma unroll
        for (int i = 0; i < 8; i++) {
            float cf = (e0 + i < end) ? (float)(en[i] & 0x7fffu) * 3.051850947599719e-05f : 0.0f;
            ax = fmaf(cf, v[i].x, ax);
            ay = fmaf(cf, v[i].y, ay);
        }
    }
    const int lane2 = lane * 2;
    float2 bv = *(const float2*)&bias[lane2];
    ax = fmaxf(ax + bv.x, 0.f);
    ay = fmaxf(ay + bv.y, 0.f);
    if constexpr (OBF16) {
        ((unsigned int*)outv)[(size_t)node * 64 + lane] = f2bf2(ax, ay);
    } else {
        *(float2*)&((float*)outv)[(size_t)node * 128 + lane2] = make_float2(ax, ay);
    }
}

// ---------------------------------------------------------------------------
extern "C" void kernel_launch(void* const* d_in, const int* in_sizes, int n_in,
                              void* d_out, int out_size, void* d_ws, size_t ws_size,
                              hipStream_t stream) {
    const float* x   = (const float*)d_in[0];
    const int*   ei  = (const int*)d_in[1];
    const float* ew  = (const float*)d_in[2];
    const float* W1  = (const float*)d_in[3];
    const float* b1  = (const float*)d_in[4];
    const float* W2  = (const float*)d_in[5];
    const float* b2  = (const float*)d_in[6];
    const float* Wfc = (const float*)d_in[7];
    const float* bfc = (const float*)d_in[8];
    float* out = (float*)d_out;

    char* ws = (char*)d_ws;
    size_t o = 0;
    auto alloc = [&](size_t bytes) { char* p = ws + o; o += (bytes + 255) & ~255ull; return p; };
    unsigned long long* packed = (unsigned long long*)alloc((size_t)N_NODES * 8);
    float* dinv  = (float*)alloc((size_t)N_NODES * 4);
    int*   cnt   = (int*)  alloc((size_t)N_NODES * 4);
    int*   off   = (int*)  alloc((size_t)N_NODES * 4);
    int*   cur   = (int*)  alloc((size_t)N_NODES * 4);
    int*   flag  = (int*)  alloc(256);
    int*   bsum  = (int*)  alloc((size_t)NSCAN * 4);
    int*   bex   = (int*)  alloc((size_t)NSCAN * 4);
    unsigned int*   sedge = (unsigned int*)alloc((size_t)N_EDGES * 4);
    unsigned short* W1t   = (unsigned short*)alloc(128 * 128 * 2);
    unsigned short* W2t   = (unsigned short*)alloc(128 * 128 * 2);
    unsigned short* hbf   = (unsigned short*)alloc((size_t)N_NODES * 128 * 2);  // gemm out
    unsigned short* aggb  = (unsigned short*)alloc((size_t)N_NODES * 128 * 2);  // agg1 out
    float*          aggf  = (float*)alloc((size_t)N_NODES * 128 * 4);           // agg2 out

    const int EB = (N_EDGES + 255) / 256;
    const int NB = (N_NODES + 255) / 256;

    int hint64 = (in_sizes[1] == 4 * N_EDGES) ? 1 : 0;
    k_detect<<<1, 256, 0, stream>>>(ei, flag, hint64);
    k_init<<<NB, 256, 0, stream>>>(packed);
    k_castw<<<64, 256, 0, stream>>>(W1, W1t);
    k_castw<<<64, 256, 0, stream>>>(W2, W2t);
    k_hist<<<EB, 256, 0, stream>>>(ei, flag, ew, packed);
    k_scan_a<<<NSCAN, 256, 0, stream>>>(packed, cnt, dinv, bsum);
    k_scan_b<<<1, 128, 0, stream>>>(bsum, bex);
    k_scan_c<<<NSCAN, 256, 0, stream>>>(cnt, bex, off, cur);
    k_scatter<<<EB, 256, 0, stream>>>(ei, flag, ew, dinv, cur, sedge);

    const int GB = (N_NODES + 127) / 128;        // 782
    const int AB = (N_NODES * 64 + 255) / 256;   // 1 wave per node

    k_gemm_mfma<false><<<GB, 256, 0, stream>>>(x, W1t, hbf);
    k_aggregate<true><<<AB, 256, 0, stream>>>((const unsigned int*)hbf, sedge, off, cnt, dinv, b1, aggb);
    k_gemm_mfma<true><<<GB, 256, 0, stream>>>(aggb, W2t, hbf);
    k_aggregate<false><<<AB, 256, 0, stream>>>((const unsigned int*)hbf, sedge, off, cnt, dinv, b2, aggf);
    k_gemm<64><<<GB, 256, 0, stream>>>(aggf, Wfc, bfc, out);
}

// Round 8
// 452.644 us; speedup vs baseline: 2.0761x; 1.0619x over previous
//
#include <hip/hip_runtime.h>
#include <math.h>

#define N_NODES 100000
#define N_EDGES 1600000
#define SCAN_CHUNK 1024
#define NSCAN ((N_NODES + SCAN_CHUNK - 1) / SCAN_CHUNK)   // 98
#define WMASK ((1ull << 40) - 1)
#define LDSW 136   // LDS row stride in shorts: 272B, 16B-aligned, bank-spread
#define BINSHIFT 9
#define NBINS 196                 // ceil(100000 / 512)
#define BINCAP 12288              // mean 8163 + ~45 sigma — no overflow possible
#define BIN_BLOCKS 512
#define EPT 13                    // edges/thread; 512*256*13 = 1,703,936 >= E
// D_IN = D_HID = 128, D_OUT = 64

typedef short bf16x8 __attribute__((ext_vector_type(8)));
typedef float f32x4 __attribute__((ext_vector_type(4)));

// ---------------------------------------------------------------------------
// bf16 helpers (packed uint: low 16 = even dim, high = odd dim; RNE casts)
__device__ __forceinline__ float2 bf2f(unsigned int u) {
    float2 r;
    r.x = __uint_as_float(u << 16);
    r.y = __uint_as_float(u & 0xffff0000u);
    return r;
}
__device__ __forceinline__ unsigned int f2bf2(float a, float b) {
    unsigned int ua = __float_as_uint(a), ub = __float_as_uint(b);
    ua += 0x7fffu + ((ua >> 16) & 1u);
    ub += 0x7fffu + ((ub >> 16) & 1u);
    return (ua >> 16) | (ub & 0xffff0000u);
}
__device__ __forceinline__ unsigned short f2bf(float a) {
    unsigned int u = __float_as_uint(a);
    u += 0x7fffu + ((u >> 16) & 1u);
    return (unsigned short)(u >> 16);
}

// ---------------------------------------------------------------------------
// Edge-index dtype detection (int64 per reference vs int32 per harness doc).
__global__ void k_detect(const int* __restrict__ ei, int* __restrict__ flag, int host_hint) {
    __shared__ int s_cnt;
    if (threadIdx.x == 0) s_cnt = 0;
    __syncthreads();
    int local = 0;
    for (int e = threadIdx.x; e < 4096; e += blockDim.x)
        if (ei[2 * e + 1] != 0) local++;
    atomicAdd(&s_cnt, local);
    __syncthreads();
    if (threadIdx.x == 0) flag[0] = (host_hint || s_cnt < 100) ? 1 : 0;
}

__global__ void k_init(unsigned long long* __restrict__ packed, int* __restrict__ gbincur) {
    int i = blockIdx.x * blockDim.x + threadIdx.x;
    if (i < N_NODES) packed[i] = 0ull;
    if (i < NBINS) gbincur[i] = i * BINCAP;
}

// ---------------------------------------------------------------------------
// Phase 1: decode edges once (register stash), packed degree-histogram atomic,
// and multisplit into 196 destination-range bins with block-grouped writes.
__global__ __launch_bounds__(256) void k_bin(const int* __restrict__ ei32,
                                             const int* __restrict__ flag,
                                             const float* __restrict__ ew,
                                             unsigned long long* __restrict__ packed,
                                             int* __restrict__ gbincur,
                                             uint2* __restrict__ binstage) {
    __shared__ int scnt[256];
    __shared__ int sbase[256];
    const int tid = threadIdx.x;
    scnt[tid] = 0;
    const bool f64 = flag[0] != 0;
    const long long base = (long long)blockIdx.x * (256 * EPT);
    unsigned int ea[EPT], eb[EPT];
    __syncthreads();
    #pragma unroll
    for (int i = 0; i < EPT; i++) {
        long long e = base + (long long)i * 256 + tid;
        bool ok = e < N_EDGES;
        int r = 0, c = 0;
        float w = 0.f;
        if (ok) {
            if (f64) {
                const long long* p64 = (const long long*)ei32;
                r = (int)p64[e];
                c = (int)p64[N_EDGES + e];
            } else {
                r = ei32[e];
                c = ei32[N_EDGES + e];
            }
            w = ew[e];
            unsigned long long wfix = (unsigned long long)(w * 4294967296.0f);  // *2^32
            atomicAdd(&packed[c], (1ull << 40) | wfix);
            atomicAdd(&scnt[c >> BINSHIFT], 1);
        }
        unsigned int wq = (unsigned int)(w * 32767.0f + 0.5f);   // Q0.15, w<1
        ea[i] = ok ? (((unsigned int)c << 15) | wq) : 0xffffffffu;  // c<2^17 => sentinel safe
        eb[i] = (unsigned int)r;
    }
    __syncthreads();
    {
        int n = scnt[tid];
        if (tid < NBINS && n > 0) sbase[tid] = atomicAdd(&gbincur[tid], n);
        scnt[tid] = 0;      // own-slot reuse as running offset
    }
    __syncthreads();
    #pragma unroll
    for (int i = 0; i < EPT; i++) {
        if (ea[i] != 0xffffffffu) {
            int bin = (int)(ea[i] >> (15 + BINSHIFT));
            int slot = atomicAdd(&scnt[bin], 1);
            binstage[sbase[bin] + slot] = make_uint2(ea[i], eb[i]);
        }
    }
}

// ---------------------------------------------------------------------------
// Scan stage A fused with unpack: packed -> cnt, dinv, per-chunk sums.
__global__ __launch_bounds__(256) void k_scan_a(const unsigned long long* __restrict__ packed,
                                                int* __restrict__ cnt,
                                                float* __restrict__ dinv,
                                                int* __restrict__ bsum) {
    __shared__ int sred[4];
    const int b = blockIdx.x, tid = threadIdx.x;
    const int base = b * SCAN_CHUNK;
    int s = 0;
    #pragma unroll
    for (int i = 0; i < 4; i++) {
        int idx = base + tid + i * 256;
        if (idx < N_NODES) {
            unsigned long long p = packed[idx];
            int c = (int)(p >> 40);
            float deg = 1.0f + (float)(p & WMASK) * 2.3283064365386963e-10f;  // 2^-32
            cnt[idx] = c;
            dinv[idx] = rsqrtf(deg);   // deg >= 1 always (self loop)
            s += c;
        }
    }
    #pragma unroll
    for (int sh = 1; sh < 64; sh <<= 1) s += __shfl_xor(s, sh);
    if ((tid & 63) == 0) sred[tid >> 6] = s;
    __syncthreads();
    if (tid == 0) bsum[b] = sred[0] + sred[1] + sred[2] + sred[3];
}

__global__ __launch_bounds__(128) void k_scan_b(const int* __restrict__ bsum,
                                                int* __restrict__ bex) {
    __shared__ int wsum[2];
    const int tid = threadIdx.x, lane = tid & 63, w = tid >> 6;
    int v = (tid < NSCAN) ? bsum[tid] : 0;
    int x = v;
    #pragma unroll
    for (int sh = 1; sh < 64; sh <<= 1) {
        int t = __shfl_up(x, sh);
        if (lane >= sh) x += t;
    }
    if (lane == 63) wsum[w] = x;
    __syncthreads();
    int add = (w == 1) ? wsum[0] : 0;
    if (tid < NSCAN) bex[tid] = x - v + add;
}

__global__ __launch_bounds__(256) void k_scan_c(const int* __restrict__ cnt,
                                                const int* __restrict__ bex,
                                                int* __restrict__ off,
                                                int* __restrict__ cur) {
    __shared__ int swave[4];
    const int b = blockIdx.x, tid = threadIdx.x;
    const int base = b * SCAN_CHUNK + tid * 4;
    int4 v = make_int4(0, 0, 0, 0);
    if (base + 3 < N_NODES) v = *(const int4*)&cnt[base];
    else {
        if (base + 0 < N_NODES) v.x = cnt[base + 0];
        if (base + 1 < N_NODES) v.y = cnt[base + 1];
        if (base + 2 < N_NODES) v.z = cnt[base + 2];
    }
    const int tsum = v.x + v.y + v.z + v.w;
    const int lane = tid & 63, w = tid >> 6;
    int x = tsum;
    #pragma unroll
    for (int sh = 1; sh < 64; sh <<= 1) {
        int t = __shfl_up(x, sh);
        if (lane >= sh) x += t;
    }
    if (lane == 63) swave[w] = x;
    __syncthreads();
    int wadd = 0;
    for (int i = 0; i < w; i++) wadd += swave[i];
    const int ex = bex[b] + wadd + (x - tsum);
    const int p0 = ex, p1 = p0 + v.x, p2 = p1 + v.y, p3 = p2 + v.z;
    if (base + 3 < N_NODES) {
        *(int4*)&off[base] = make_int4(p0, p1, p2, p3);
        *(int4*)&cur[base] = make_int4(p0, p1, p2, p3);
    } else {
        if (base + 0 < N_NODES) { off[base + 0] = p0; cur[base + 0] = p0; }
        if (base + 1 < N_NODES) { off[base + 1] = p1; cur[base + 1] = p1; }
        if (base + 2 < N_NODES) { off[base + 2] = p2; cur[base + 2] = p2; }
    }
}

// ---------------------------------------------------------------------------
// Phase 2: per-bin local scatter. All cursor atomics hit a 512-node window,
// all sedge writes hit a ~32KB window -> L2-resident, full-line writebacks.
__global__ __launch_bounds__(256) void k_csr(const int* __restrict__ gbincur,
                                             const uint2* __restrict__ binstage,
                                             const float* __restrict__ dinv,
                                             int* __restrict__ cur,
                                             unsigned int* __restrict__ sedge) {
    const int bin = blockIdx.x >> 1;
    const int half = blockIdx.x & 1;
    const int s0 = bin * BINCAP;
    const int total = gbincur[bin] - s0;
    for (int i = half * 256 + threadIdx.x; i < total; i += 512) {
        uint2 en = binstage[s0 + i];
        int c = (int)(en.x >> 15);
        float w = (float)(en.x & 0x7fffu) * 3.051850947599719e-05f;   // /32767
        int r = (int)en.y;
        float coef = dinv[c] * dinv[r] * w;
        unsigned int q = (unsigned int)(coef * 32767.0f + 0.5f);
        if (q > 32767u) q = 32767u;
        int p = atomicAdd(&cur[c], 1);
        sedge[p] = ((unsigned int)r << 15) | q;
    }
}

// ---------------------------------------------------------------------------
// W[128][128] f32 -> Wt[n][k] bf16 (transposed so B-fragments are contiguous).
__global__ void k_castw(const float* __restrict__ W, unsigned short* __restrict__ Wt) {
    int i = blockIdx.x * blockDim.x + threadIdx.x;   // 16384
    int k = i >> 7, n = i & 127;
    Wt[n * 128 + k] = f2bf(W[k * 128 + n]);
}

// ---------------------------------------------------------------------------
// MFMA GEMM: C[n,128] = A[n,128] @ W[128,128], bf16 in, f32 accum, bf16 out.
template <bool ABF16>
__global__ __launch_bounds__(256) void k_gemm_mfma(const void* __restrict__ Av,
                                                   const unsigned short* __restrict__ Wt,
                                                   unsigned short* __restrict__ Cb) {
    __shared__ unsigned short Al[128 * LDSW];
    __shared__ unsigned short Wl[128 * LDSW];
    const int tid = threadIdx.x;
    const int srow = tid >> 1, h = tid & 1;
    const int r0 = blockIdx.x * 128;

    {
        const uint4* src = (const uint4*)&Wt[srow * 128 + h * 64];
        uint4* dst = (uint4*)&Wl[srow * LDSW + h * 64];
        #pragma unroll
        for (int c = 0; c < 8; c++) dst[c] = src[c];
    }
    {
        const bool ok = (r0 + srow) < N_NODES;
        uint4* dst = (uint4*)&Al[srow * LDSW + h * 64];
        if constexpr (ABF16) {
            const uint4* src = (const uint4*)((const unsigned short*)Av +
                                              (size_t)(r0 + srow) * 128 + h * 64);
            uint4 z = make_uint4(0, 0, 0, 0);
            #pragma unroll
            for (int c = 0; c < 8; c++) dst[c] = ok ? src[c] : z;
        } else {
            const float* src = (const float*)Av + (size_t)(r0 + srow) * 128 + h * 64;
            #pragma unroll
            for (int c = 0; c < 8; c++) {
                float4 f0 = ok ? *(const float4*)&src[c * 8]     : make_float4(0, 0, 0, 0);
                float4 f1 = ok ? *(const float4*)&src[c * 8 + 4] : make_float4(0, 0, 0, 0);
                uint4 pk;
                pk.x = f2bf2(f0.x, f0.y);
                pk.y = f2bf2(f0.z, f0.w);
                pk.z = f2bf2(f1.x, f1.y);
                pk.w = f2bf2(f1.z, f1.w);
                dst[c] = pk;
            }
        }
    }
    __syncthreads();

    const int lane = tid & 63;
    const int w = tid >> 6;
    const int lr = lane & 15;
    const int kg = lane >> 4;
    f32x4 acc[2][8] = {};

    #pragma unroll
    for (int k0 = 0; k0 < 128; k0 += 32) {
        const int kb = k0 + kg * 8;
        bf16x8 a0 = *(const bf16x8*)&Al[(w * 32 + lr) * LDSW + kb];
        bf16x8 a1 = *(const bf16x8*)&Al[(w * 32 + 16 + lr) * LDSW + kb];
        #pragma unroll
        for (int ct = 0; ct < 8; ct++) {
            bf16x8 b = *(const bf16x8*)&Wl[(ct * 16 + lr) * LDSW + kb];
            acc[0][ct] = __builtin_amdgcn_mfma_f32_16x16x32_bf16(a0, b, acc[0][ct], 0, 0, 0);
            acc[1][ct] = __builtin_amdgcn_mfma_f32_16x16x32_bf16(a1, b, acc[1][ct], 0, 0, 0);
        }
    }

    #pragma unroll
    for (int rt = 0; rt < 2; rt++)
        #pragma unroll
        for (int r = 0; r < 4; r++) {
            int row = r0 + w * 32 + rt * 16 + kg * 4 + r;
            if (row < N_NODES) {
                #pragma unroll
                for (int ct = 0; ct < 8; ct++)
                    Cb[(size_t)row * 128 + ct * 16 + lr] = f2bf(acc[rt][ct][r]);
            }
        }
}

// ---------------------------------------------------------------------------
// Vector-f32 GEMM for the fc head: C[n,64] = A[n,128] @ Wfc + bias, sigmoid.
template <int DOUT>
__global__ __launch_bounds__(256) void k_gemm(const float* __restrict__ A,
                                              const float* __restrict__ W,
                                              const float* __restrict__ bias,
                                              float* __restrict__ C) {
    constexpr int CPT = DOUT / 16;
    __shared__ float Ws[128 * DOUT];
    __shared__ float As[8][128];
    const int tid = threadIdx.x;
    const int tx = tid & 15, ty = tid >> 4;

    for (int i = tid * 4; i < 128 * DOUT; i += 256 * 4)
        *(float4*)&Ws[i] = *(const float4*)&W[i];

    const int r0 = blockIdx.x * 128;
    const int arow = tid >> 1;
    const int ak = (tid & 1) * 4;
    const bool rowok = (r0 + arow) < N_NODES;

    float acc[8][CPT];
    #pragma unroll
    for (int i = 0; i < 8; i++)
        #pragma unroll
        for (int j = 0; j < CPT; j++) acc[i][j] = 0.f;

    for (int k0 = 0; k0 < 128; k0 += 8) {
        float4 av = make_float4(0.f, 0.f, 0.f, 0.f);
        if (rowok) av = *(const float4*)&A[(size_t)(r0 + arow) * 128 + k0 + ak];
        __syncthreads();
        As[ak + 0][arow] = av.x;
        As[ak + 1][arow] = av.y;
        As[ak + 2][arow] = av.z;
        As[ak + 3][arow] = av.w;
        __syncthreads();
        #pragma unroll
        for (int kk = 0; kk < 8; kk++) {
            float4 a0 = *(const float4*)&As[kk][ty * 8];
            float4 a1 = *(const float4*)&As[kk][ty * 8 + 4];
            float av8[8] = {a0.x, a0.y, a0.z, a0.w, a1.x, a1.y, a1.z, a1.w};
            float wv[CPT];
            float4 w0 = *(const float4*)&Ws[(k0 + kk) * DOUT + tx * CPT];
            wv[0] = w0.x; wv[1] = w0.y; wv[2] = w0.z; wv[3] = w0.w;
            #pragma unroll
            for (int i = 0; i < 8; i++)
                #pragma unroll
                for (int j = 0; j < CPT; j++)
                    acc[i][j] = fmaf(av8[i], wv[j], acc[i][j]);
        }
    }

    #pragma unroll
    for (int i = 0; i < 8; i++) {
        int r = r0 + ty * 8 + i;
        if (r < N_NODES) {
            float vout[CPT];
            #pragma unroll
            for (int j = 0; j < CPT; j++) {
                float v = acc[i][j] + bias[tx * CPT + j];
                vout[j] = 1.0f / (1.0f + expf(-v));
            }
            #pragma unroll
            for (int j = 0; j < CPT; j += 4)
                *(float4*)&C[(size_t)r * DOUT + tx * CPT + j] =
                    make_float4(vout[j], vout[j + 1], vout[j + 2], vout[j + 3]);
        }
    }
}

// ---------------------------------------------------------------------------
// Pull aggregation over bf16 rows; OBF16 selects bf16-packed vs f32 output.
template <bool OBF16>
__global__ __launch_bounds__(256) void k_aggregate(const unsigned int* __restrict__ lin,
                                                   const unsigned int* __restrict__ sedge,
                                                   const int* __restrict__ off,
                                                   const int* __restrict__ cnt,
                                                   const float* __restrict__ dinv,
                                                   const float* __restrict__ bias,
                                                   void* __restrict__ outv) {
    const int node = (blockIdx.x * 256 + threadIdx.x) >> 6;
    const int lane = threadIdx.x & 63;
    if (node >= N_NODES) return;
    const float di = dinv[node];
    float2 sv = bf2f(lin[(size_t)node * 64 + lane]);
    float ax = di * di * sv.x;
    float ay = di * di * sv.y;
    const int start = __builtin_amdgcn_readfirstlane(off[node]);
    const int end = start + __builtin_amdgcn_readfirstlane(cnt[node]);
    for (int e0 = start; e0 < end; e0 += 8) {
        unsigned int en[8];
        #pragma unroll
        for (int i = 0; i < 8; i++) {
            int idx = e0 + i;
            en[i] = sedge[idx < end ? idx : end - 1];
        }
        float2 v[8];
        #pragma unroll
        for (int i = 0; i < 8; i++)
            v[i] = bf2f(lin[(size_t)(en[i] >> 15) * 64 + lane]);
        #pragma unroll
        for (int i = 0; i < 8; i++) {
            float cf = (e0 + i < end) ? (float)(en[i] & 0x7fffu) * 3.051850947599719e-05f : 0.0f;
            ax = fmaf(cf, v[i].x, ax);
            ay = fmaf(cf, v[i].y, ay);
        }
    }
    const int lane2 = lane * 2;
    float2 bv = *(const float2*)&bias[lane2];
    ax = fmaxf(ax + bv.x, 0.f);
    ay = fmaxf(ay + bv.y, 0.f);
    if constexpr (OBF16) {
        ((unsigned int*)outv)[(size_t)node * 64 + lane] = f2bf2(ax, ay);
    } else {
        *(float2*)&((float*)outv)[(size_t)node * 128 + lane2] = make_float2(ax, ay);
    }
}

// ---------------------------------------------------------------------------
extern "C" void kernel_launch(void* const* d_in, const int* in_sizes, int n_in,
                              void* d_out, int out_size, void* d_ws, size_t ws_size,
                              hipStream_t stream) {
    const float* x   = (const float*)d_in[0];
    const int*   ei  = (const int*)d_in[1];
    const float* ew  = (const float*)d_in[2];
    const float* W1  = (const float*)d_in[3];
    const float* b1  = (const float*)d_in[4];
    const float* W2  = (const float*)d_in[5];
    const float* b2  = (const float*)d_in[6];
    const float* Wfc = (const float*)d_in[7];
    const float* bfc = (const float*)d_in[8];
    float* out = (float*)d_out;

    char* ws = (char*)d_ws;
    size_t o = 0;
    auto alloc = [&](size_t bytes) { char* p = ws + o; o += (bytes + 255) & ~255ull; return p; };
    unsigned long long* packed = (unsigned long long*)alloc((size_t)N_NODES * 8);
    float* dinv  = (float*)alloc((size_t)N_NODES * 4);
    int*   cnt   = (int*)  alloc((size_t)N_NODES * 4);
    int*   off   = (int*)  alloc((size_t)N_NODES * 4);
    int*   cur   = (int*)  alloc((size_t)N_NODES * 4);
    int*   flag  = (int*)  alloc(256);
    int*   bsum  = (int*)  alloc((size_t)NSCAN * 4);
    int*   bex   = (int*)  alloc((size_t)NSCAN * 4);
    int*   gbincur = (int*)alloc(256 * 4);
    unsigned int*   sedge = (unsigned int*)alloc((size_t)N_EDGES * 4);
    unsigned short* W1t   = (unsigned short*)alloc(128 * 128 * 2);
    unsigned short* W2t   = (unsigned short*)alloc(128 * 128 * 2);
    // Liveness aliasing: binstage dead before hbf born (k_csr < gemm1);
    // aggb (agg1 out, dead after gemm2) aliases aggf (born at agg2).
    char* region1 = alloc((size_t)N_NODES * 128 * 2);             // 25.6 MB
    uint2*          binstage = (uint2*)region1;                   // 19.3 MB used
    unsigned short* hbf      = (unsigned short*)region1;
    float*          aggf = (float*)alloc((size_t)N_NODES * 128 * 4);
    unsigned short* aggb = (unsigned short*)aggf;

    const int NB = (N_NODES + 255) / 256;

    int hint64 = (in_sizes[1] == 4 * N_EDGES) ? 1 : 0;
    k_detect<<<1, 256, 0, stream>>>(ei, flag, hint64);
    k_init<<<NB, 256, 0, stream>>>(packed, gbincur);
    k_castw<<<64, 256, 0, stream>>>(W1, W1t);
    k_castw<<<64, 256, 0, stream>>>(W2, W2t);
    k_bin<<<BIN_BLOCKS, 256, 0, stream>>>(ei, flag, ew, packed, gbincur, binstage);
    k_scan_a<<<NSCAN, 256, 0, stream>>>(packed, cnt, dinv, bsum);
    k_scan_b<<<1, 128, 0, stream>>>(bsum, bex);
    k_scan_c<<<NSCAN, 256, 0, stream>>>(cnt, bex, off, cur);
    k_csr<<<NBINS * 2, 256, 0, stream>>>(gbincur, binstage, dinv, cur, sedge);

    const int GB = (N_NODES + 127) / 128;        // 782
    const int AB = (N_NODES * 64 + 255) / 256;   // 1 wave per node

    k_gemm_mfma<false><<<GB, 256, 0, stream>>>(x, W1t, hbf);
    k_aggregate<true><<<AB, 256, 0, stream>>>((const unsigned int*)hbf, sedge, off, cnt, dinv, b1, aggb);
    k_gemm_mfma<true><<<GB, 256, 0, stream>>>(aggb, W2t, hbf);
    k_aggregate<false><<<AB, 256, 0, stream>>>((const unsigned int*)hbf, sedge, off, cnt, dinv, b2, aggf);
    k_gemm<64><<<GB, 256, 0, stream>>>(aggf, Wfc, bfc, out);
}